// Round 8
// baseline (586.430 us; speedup 1.0000x reference)
//
#include <hip/hip_runtime.h>
#include <hip/hip_bf16.h>
#include <cstdint>
#include <cstddef>

// ---------------------------------------------------------------------------
// SAGE GNN forward, bf16 MFMA 32x32x16, LDS-staged GEMM, BK=64.
//  - round-6 schedule (wait0/barrier/stage(t+1)/compute) -- proven fastest
//  - NEW: internal column-chunk loop (L3/L4): A re-reads hit own-XCD L2
//  - A tile [128][128B] XOR-swizzled; B pre-packed chunk-major
// ---------------------------------------------------------------------------

typedef short bf16x8 __attribute__((ext_vector_type(8)));   // 8 bf16 = 4 VGPRs
typedef float f32x16 __attribute__((ext_vector_type(16)));

static inline int idiv_up(int a, int b) { return (a + b - 1) / b; }

static __device__ __forceinline__ float bf2f(unsigned short u) {
  union { unsigned int i; float f; } v; v.i = ((unsigned int)u) << 16; return v.f;
}
static __device__ __forceinline__ unsigned short f2bf(float f) {
  union { float f; unsigned int i; } v; v.f = f;
  return (unsigned short)((v.i + 0x7FFFu + ((v.i >> 16) & 1u)) >> 16);  // RNE
}
static __device__ __forceinline__ float lo16(unsigned int u) { return bf2f((unsigned short)(u & 0xffffu)); }
static __device__ __forceinline__ float hi16(unsigned int u) { return bf2f((unsigned short)(u >> 16)); }
static __device__ __forceinline__ unsigned int packbf(float a, float b) {
  return (unsigned int)f2bf(a) | ((unsigned int)f2bf(b) << 16);
}

// async global->LDS, 16B per lane. LDS dest: wave-uniform base + lane*16.
static __device__ __forceinline__ void gl_lds16(const void* g, void* l) {
  typedef __attribute__((address_space(3))) unsigned int lds_u32;
  typedef __attribute__((address_space(1))) const unsigned int glb_u32;
  __builtin_amdgcn_global_load_lds((glb_u32*)(uintptr_t)g,
                                   (lds_u32*)(unsigned int)(uintptr_t)l, 16, 0, 0);
}

// ---------------- CSR build ----------------
__global__ void k_count_deg(const int* __restrict__ dst, int* __restrict__ deg, int E) {
  int e = blockIdx.x * blockDim.x + threadIdx.x;
  if (e < E) atomicAdd(deg + dst[e], 1);
}

// wave-shfl hierarchical scan, 1024 threads, chunked.
__global__ __launch_bounds__(1024)
void k_scan(const int* __restrict__ deg, int* __restrict__ row_off, int* __restrict__ cursor,
            float* __restrict__ deg_inv, int n) {
  __shared__ int wsum[16];
  const int tid = threadIdx.x;
  const int lane = tid & 63, wid = tid >> 6;
  int carry = 0;
  for (int base = 0; base < n; base += 1024) {
    const int i = base + tid;
    const int v = (i < n) ? deg[i] : 0;
    int incl = v;
#pragma unroll
    for (int off = 1; off < 64; off <<= 1) {
      int t = __shfl_up(incl, off);
      if (lane >= off) incl += t;
    }
    if (lane == 63) wsum[wid] = incl;
    __syncthreads();
    if (wid == 0) {
      int wv = (lane < 16) ? wsum[lane] : 0;
#pragma unroll
      for (int off = 1; off < 16; off <<= 1) {
        int t = __shfl_up(wv, off);
        if (lane >= off) wv += t;
      }
      if (lane < 16) wsum[lane] = wv;
    }
    __syncthreads();
    const int woff = (wid > 0) ? wsum[wid - 1] : 0;
    if (i < n) {
      const int ro = carry + woff + incl - v;
      row_off[i] = ro;
      cursor[i] = ro;
      deg_inv[i] = 1.0f / (float)((v > 1) ? v : 1);
    }
    const int tot = wsum[15];
    __syncthreads();
    carry += tot;
  }
  if (tid == 0) row_off[n] = carry;
}

__global__ void k_fill_csr(const int* __restrict__ src, const int* __restrict__ dst,
                           int* __restrict__ cursor, int* __restrict__ esrc, int E) {
  int e = blockIdx.x * blockDim.x + threadIdx.x;
  if (e < E) {
    int d = dst[e];
    int p = atomicAdd(cursor + d, 1);
    esrc[p] = src[e];
  }
}

// ---------------- x: f32 -> bf16 plain conversion --------------------------
__global__ __launch_bounds__(256)
void k_conv_x(const float* __restrict__ src, unsigned short* __restrict__ dst, int n4) {
  for (int i = blockIdx.x * blockDim.x + threadIdx.x; i < n4; i += gridDim.x * blockDim.x) {
    const float4 v = *((const float4*)src + i);
    uint2 o;
    o.x = packbf(v.x, v.y);
    o.y = packbf(v.z, v.w);
    *((uint2*)dst + i) = o;
  }
}

// ---------------- weights: f32 -> bf16 packed chunk-major ------------------
// dst elem index = kt64*(O*64) + chunk*(O*8) + col*8 + j  holds
// src[col][kt64*64 + chunk*8 + j]  (chunk in 0..7)
struct PackJob { const float* src; unsigned short* dst; int O; int K; };
struct PackJobs { PackJob j[10]; };

__global__ __launch_bounds__(256)
void k_pack_w(PackJobs jobs) {
  const PackJob J = jobs.j[blockIdx.y];
  const int total = J.O * J.K / 2;  // u32 outputs
  const int OK64 = J.O * 64;
  for (int u = blockIdx.x * blockDim.x + threadIdx.x; u < total; u += gridDim.x * blockDim.x) {
    const int e = u * 2;
    const int kt = e / OK64;
    const int rem = e - kt * OK64;
    const int chunk = rem / (J.O * 8);
    const int rem2 = rem - chunk * (J.O * 8);
    const int col = rem2 >> 3;
    const int j = rem2 & 7;
    const int korig = kt * 64 + chunk * 8 + j;
    const float f0 = J.src[(size_t)col * J.K + korig];
    const float f1 = J.src[(size_t)col * J.K + korig + 1];
    ((unsigned int*)J.dst)[u] = packbf(f0, f1);
  }
}

// ---------------- mean aggregation, bf16 in/out, f32 accum -----------------
__global__ __launch_bounds__(256)
void k_agg128(const unsigned short* __restrict__ h, const int* __restrict__ row_off,
              const int* __restrict__ esrc, const float* __restrict__ deg_inv,
              unsigned short* __restrict__ agg, int N) {
  const int node = blockIdx.x * 4 + (threadIdx.x >> 6);
  if (node >= N) return;
  const int lane = threadIdx.x & 63;
  const int s0 = row_off[node], s1 = row_off[node + 1];
  const unsigned int* hp = (const unsigned int*)h;
  float al = 0.f, ah = 0.f;
  for (int i = s0; i < s1; i += 8) {
    unsigned int u[8];
#pragma unroll
    for (int j = 0; j < 8; ++j) {
      const int e = (i + j < s1) ? (i + j) : i;
      u[j] = hp[(size_t)esrc[e] * 64 + lane];
    }
#pragma unroll
    for (int j = 0; j < 8; ++j)
      if (i + j < s1) { al += lo16(u[j]); ah += hi16(u[j]); }
  }
  const float di = deg_inv[node];
  ((unsigned int*)agg)[(size_t)node * 64 + lane] = packbf(al * di, ah * di);
}

__global__ __launch_bounds__(256)
void k_agg256(const unsigned short* __restrict__ h, const int* __restrict__ row_off,
              const int* __restrict__ esrc, const float* __restrict__ deg_inv,
              unsigned short* __restrict__ agg, int N) {
  const int node = blockIdx.x * 4 + (threadIdx.x >> 6);
  if (node >= N) return;
  const int lane = threadIdx.x & 63;
  const int s0 = row_off[node], s1 = row_off[node + 1];
  const unsigned int* hp = (const unsigned int*)h;
  float al = 0.f, ah = 0.f, bl_ = 0.f, bh = 0.f;
  for (int i = s0; i < s1; i += 4) {
    unsigned int u0[4], u1[4];
#pragma unroll
    for (int j = 0; j < 4; ++j) {
      const int e = (i + j < s1) ? (i + j) : i;
      const size_t b = (size_t)esrc[e] * 128;
      u0[j] = hp[b + lane];
      u1[j] = hp[b + 64 + lane];
    }
#pragma unroll
    for (int j = 0; j < 4; ++j)
      if (i + j < s1) {
        al += lo16(u0[j]); ah += hi16(u0[j]);
        bl_ += lo16(u1[j]); bh += hi16(u1[j]);
      }
  }
  const float di = deg_inv[node];
  unsigned int* ap = (unsigned int*)agg;
  ap[(size_t)node * 128 + lane] = packbf(al * di, ah * di);
  ap[(size_t)node * 128 + 64 + lane] = packbf(bl_ * di, bh * di);
}

__global__ __launch_bounds__(256)
void k_agg64(const unsigned short* __restrict__ h, const int* __restrict__ row_off,
             const int* __restrict__ esrc, const float* __restrict__ deg_inv,
             unsigned short* __restrict__ agg, int N) {
  const int node = blockIdx.x * 4 + (threadIdx.x >> 6);
  if (node >= N) return;
  const int lane = threadIdx.x & 63;
  const int half = lane >> 5, c = lane & 31;
  const int s0 = row_off[node], s1 = row_off[node + 1];
  const unsigned int* hp = (const unsigned int*)h;
  float al = 0.f, ah = 0.f;
  for (int i = s0 + half; i < s1; i += 8) {  // this half: i, i+2, i+4, i+6
    unsigned int u[4];
#pragma unroll
    for (int j = 0; j < 4; ++j) {
      const int idx = i + 2 * j;
      const int e = (idx < s1) ? idx : i;
      u[j] = hp[(size_t)esrc[e] * 32 + c];
    }
#pragma unroll
    for (int j = 0; j < 4; ++j)
      if (i + 2 * j < s1) { al += lo16(u[j]); ah += hi16(u[j]); }
  }
  al += __shfl_xor(al, 32);
  ah += __shfl_xor(ah, 32);
  if (half == 0) {
    const float di = deg_inv[node];
    ((unsigned int*)agg)[(size_t)node * 32 + c] = packbf(al * di, ah * di);
  }
}

// ---------------- fused SAGE GEMM: C = relu(A0@B0p^T + A1@B1p^T + bias) ----
// Block: 128 rows x (NCH chunks of BN=WC*64 cols); 2 x WC waves; BK=64.
// K = KT0*64 per phase; NT = 2*KT0 tiles per chunk; NU = NCH*NT total tiles.
// Round-6 schedule: wait vmcnt(0); barrier; stage(u+1); compute(u).
// Chunk re-reads of A hit own-XCD L2 (block A footprint = 128*K*2 B).
template <int WC, int KT0, int NCH>
__global__ __launch_bounds__(WC * 128)
void k_sage_gemm(const unsigned short* __restrict__ A0, const unsigned short* __restrict__ B0,
                 const unsigned short* __restrict__ A1, const unsigned short* __restrict__ B1,
                 const float* __restrict__ bias, unsigned short* __restrict__ C,
                 int Nn, int O) {
  constexpr int KK = KT0 * 64;
  constexpr int NT = 2 * KT0;
  constexpr int NU = NCH * NT;
  constexpr int BN = WC * 64;
  constexpr int T = WC * 128;
  constexpr int ACH = 1024;            // A 16B-chunks per tile (128 rows x 8)
  constexpr int BCH = BN * 8;          // B 16B-chunks per tile
  constexpr int LPT = (ACH + BCH) / T; // chunks per thread per stage
  constexpr int BSH = (WC == 1) ? 6 : ((WC == 2) ? 7 : 8);  // log2(BN)
  constexpr int LDSBUF = 16384 + BN * 128;
  __shared__ char lds[2 * LDSBUF];

  const int tid = threadIdx.x;
  const int w = tid >> 6, lane = tid & 63;
  const int wr = w / WC, wc = w % WC;
  const int fr = lane & 31, fq = lane >> 5;
  const int row0 = blockIdx.x * 128 + wr * 64;

  f32x16 acc[2][2];
#pragma unroll
  for (int m = 0; m < 2; ++m)
#pragma unroll
    for (int cn = 0; cn < 2; ++cn)
#pragma unroll
      for (int r = 0; r < 16; ++r) acc[m][cn][r] = 0.f;

  auto stage = [&](int buf, int u) {
    const int cc = u / NT;              // column chunk (compile-time shift)
    const int t = u % NT;
    const int ph = (t >= KT0) ? 1 : 0;
    const unsigned short* Ab = ph ? A1 : A0;
    const unsigned short* Bb = ph ? B1 : B0;
    const int ktl = t - ph * KT0;
    const int colb = (blockIdx.y * NCH + cc) * BN;
    char* lb = lds + buf * LDSBUF;
#pragma unroll
    for (int i = 0; i < LPT; ++i) {
      const int ch = tid + i * T;
      if (ch < ACH) {
        const int ar = ch >> 3, s = ch & 7;         // LDS row, slot
        int g = blockIdx.x * 128 + ar;
        if (g >= Nn) g = Nn - 1;
        // inverse-swizzled global source; linear LDS dest
        gl_lds16(Ab + (size_t)g * KK + ktl * 64 + ((s ^ (ar & 7)) << 3), lb + ch * 16);
      } else {
        const int cb = ch - ACH;
        const int chunk = cb >> BSH, colrel = cb & (BN - 1);
        gl_lds16(Bb + (size_t)ktl * O * 64 + chunk * O * 8 + (colb + colrel) * 8,
                 lb + 16384 + cb * 16);
      }
    }
  };

  stage(0, 0);
#pragma unroll 1
  for (int u = 0; u < NU; ++u) {
    asm volatile("s_waitcnt vmcnt(0)" ::: "memory");
    __syncthreads();
    if (u + 1 < NU) stage((u + 1) & 1, u + 1);
    const char* lb = lds + (u & 1) * LDSBUF;
#pragma unroll
    for (int k16i = 0; k16i < 4; ++k16i) {
      const int c = k16i * 2 + fq;                  // chunk 0..7
      bf16x8 af[2], bg[2];
#pragma unroll
      for (int m = 0; m < 2; ++m) {
        const int rl = wr * 64 + m * 32 + fr;
        af[m] = *(const bf16x8*)(lb + rl * 128 + ((c ^ (rl & 7)) << 4));
      }
#pragma unroll
      for (int cn = 0; cn < 2; ++cn) {
        const int colrel = wc * 64 + cn * 32 + fr;
        bg[cn] = *(const bf16x8*)(lb + 16384 + c * (BN * 16) + colrel * 16);
      }
#pragma unroll
      for (int m = 0; m < 2; ++m)
#pragma unroll
        for (int cn = 0; cn < 2; ++cn)
          acc[m][cn] = __builtin_amdgcn_mfma_f32_32x32x16_bf16(af[m], bg[cn], acc[m][cn], 0, 0, 0);
    }
    // end of a column chunk -> epilogue + acc reset
    if ((u + 1) % NT == 0) {
      const int cc = u / NT;
      const int colb = (blockIdx.y * NCH + cc) * BN;
      // C/D map: col = lane&31, row = (reg&3) + 8*(reg>>2) + 4*(lane>>5).
#pragma unroll
      for (int cn = 0; cn < 2; ++cn) {
        const int col = colb + wc * 64 + cn * 32 + fr;
        const float bb = bias[col];
#pragma unroll
        for (int m = 0; m < 2; ++m) {
#pragma unroll
          for (int reg = 0; reg < 16; ++reg) {
            const float v = fmaxf(acc[m][cn][reg] + bb, 0.f);
            const float nb = __shfl_xor(v, 1);
            const int row = row0 + m * 32 + (reg & 3) + 8 * (reg >> 2) + 4 * fq;
            if (!(lane & 1) && row < Nn) {
              *(unsigned int*)(C + (size_t)row * O + col) = packbf(v, nb);
            }
          }
        }
      }
      if (u + 1 < NU) {
#pragma unroll
        for (int m = 0; m < 2; ++m)
#pragma unroll
          for (int cn = 0; cn < 2; ++cn)
#pragma unroll
            for (int r = 0; r < 16; ++r) acc[m][cn][r] = 0.f;
      }
    }
  }
}

// ---------------- head: logits(512->4) + softmax, 4 waves per block --------
__global__ __launch_bounds__(256)
void k_out_softmax(const unsigned short* __restrict__ h, const float* __restrict__ W4,
                   const float* __restrict__ b, float* __restrict__ out, int N) {
  const int n = blockIdx.x * 4 + (threadIdx.x >> 6);
  if (n >= N) return;
  const int lane = threadIdx.x & 63;
  const unsigned int* hp = (const unsigned int*)h + (size_t)n * 256;
  float a[4] = {0.f, 0.f, 0.f, 0.f};
#pragma unroll
  for (int it = 0; it < 4; ++it) {
    const unsigned int v = hp[it * 64 + lane];
    const float lo = lo16(v);
    const float hi = hi16(v);
    const int k = (it * 64 + lane) * 2;
#pragma unroll
    for (int c = 0; c < 4; ++c)
      a[c] += lo * W4[c * 512 + k] + hi * W4[c * 512 + k + 1];
  }
#pragma unroll
  for (int off = 32; off > 0; off >>= 1) {
#pragma unroll
    for (int c = 0; c < 4; ++c) a[c] += __shfl_down(a[c], off);
  }
  if (lane == 0) {
    const float l0 = a[0] + b[0], l1 = a[1] + b[1], l2 = a[2] + b[2], l3 = a[3] + b[3];
    const float m = fmaxf(fmaxf(l0, l1), fmaxf(l2, l3));
    const float e0 = expf(l0 - m), e1 = expf(l1 - m), e2 = expf(l2 - m), e3 = expf(l3 - m);
    const float inv = 1.0f / (e0 + e1 + e2 + e3);
    float4 r; r.x = e0 * inv; r.y = e1 * inv; r.z = e2 * inv; r.w = e3 * inv;
    *(float4*)(out + (size_t)n * 4) = r;
  }
}

// ---------------------------------------------------------------------------
extern "C" void kernel_launch(void* const* d_in, const int* in_sizes, int n_in,
                              void* d_out, int out_size, void* d_ws, size_t ws_size,
                              hipStream_t stream) {
  const float* x = (const float*)d_in[0];
  const float* Wl[5] = {(const float*)d_in[1], (const float*)d_in[4], (const float*)d_in[7],
                        (const float*)d_in[10], (const float*)d_in[13]};
  const float* bl[5] = {(const float*)d_in[2], (const float*)d_in[5], (const float*)d_in[8],
                        (const float*)d_in[11], (const float*)d_in[14]};
  const float* Wr[5] = {(const float*)d_in[3], (const float*)d_in[6], (const float*)d_in[9],
                        (const float*)d_in[12], (const float*)d_in[15]};
  const float* Wout = (const float*)d_in[16];
  const float* bout = (const float*)d_in[17];
  const int* eidx = (const int*)d_in[18];

  const int N = in_sizes[0] / 128;
  const int E = in_sizes[18] / 2;
  const int* srcI = eidx;
  const int* dstI = eidx + E;

  const int Kd[5] = {128, 128, 64, 128, 256};
  const int Od[5] = {128, 64, 128, 256, 512};

  // workspace carve-out (256B aligned)
  char* ws = (char*)d_ws;
  size_t p = 0;
  auto alloc = [&](size_t bytes) { size_t r = p; p += (bytes + 255) & ~(size_t)255; return r; };
  int*   deg     = (int*)(ws + alloc((size_t)N * 4));
  int*   row_off = (int*)(ws + alloc((size_t)(N + 1) * 4));
  int*   cursor  = (int*)(ws + alloc((size_t)N * 4));
  float* deg_inv = (float*)(ws + alloc((size_t)N * 4));
  int*   esrc    = (int*)(ws + alloc((size_t)E * 4));
  unsigned short* xb = (unsigned short*)(ws + alloc((size_t)N * 128 * 2));
  unsigned short* wlb[5];
  unsigned short* wrb[5];
  for (int l = 0; l < 5; ++l) {
    wlb[l] = (unsigned short*)(ws + alloc((size_t)Od[l] * Kd[l] * 2));
    wrb[l] = (unsigned short*)(ws + alloc((size_t)Od[l] * Kd[l] * 2));
  }
  unsigned short* bufA = (unsigned short*)(ws + alloc((size_t)N * 512 * 2));
  unsigned short* bufB = (unsigned short*)(ws + alloc((size_t)N * 256 * 2));
  unsigned short* agg  = (unsigned short*)(ws + alloc((size_t)N * 256 * 2));
  (void)ws_size; (void)n_in; (void)out_size;

  // ---- conversions: x plain; weights packed chunk-major ----
  k_conv_x<<<128, 256, 0, stream>>>(x, xb, N * 128 / 4);
  PackJobs jobs;
  for (int l = 0; l < 5; ++l) {
    jobs.j[2 * l]     = {Wl[l], wlb[l], Od[l], Kd[l]};
    jobs.j[2 * l + 1] = {Wr[l], wrb[l], Od[l], Kd[l]};
  }
  k_pack_w<<<dim3(32, 10), 256, 0, stream>>>(jobs);

  // ---- CSR build ----
  hipMemsetAsync(deg, 0, (size_t)N * 4, stream);
  k_count_deg<<<idiv_up(E, 256), 256, 0, stream>>>(dstI, deg, E);
  k_scan<<<1, 1024, 0, stream>>>(deg, row_off, cursor, deg_inv, N);
  k_fill_csr<<<idiv_up(E, 256), 256, 0, stream>>>(srcI, dstI, cursor, esrc, E);

  unsigned short* houts[5] = {bufA, bufB, bufA, bufB, bufA};

  const unsigned short* hin = xb;
  const int gx = idiv_up(N, 128);
  for (int l = 0; l < 5; ++l) {
    const int K = Kd[l], O = Od[l];
    // aggregate
    if (K == 64)
      k_agg64<<<idiv_up(N, 4), 256, 0, stream>>>(hin, row_off, esrc, deg_inv, agg, N);
    else if (K == 128)
      k_agg128<<<idiv_up(N, 4), 256, 0, stream>>>(hin, row_off, esrc, deg_inv, agg, N);
    else
      k_agg256<<<idiv_up(N, 4), 256, 0, stream>>>(hin, row_off, esrc, deg_inv, agg, N);

    // fused GEMM + bias + relu
    unsigned short* hout = houts[l];
    switch (l) {
      case 0:  // K=128, O=128: WC=2, 1 chunk
        k_sage_gemm<2, 2, 1><<<dim3(gx, 1), 256, 0, stream>>>(agg, wlb[l], hin, wrb[l], bl[l], hout, N, O);
        break;
      case 1:  // K=128, O=64: WC=1, 1 chunk
        k_sage_gemm<1, 2, 1><<<dim3(gx, 1), 128, 0, stream>>>(agg, wlb[l], hin, wrb[l], bl[l], hout, N, O);
        break;
      case 2:  // K=64, O=128: WC=2, 1 chunk
        k_sage_gemm<2, 1, 1><<<dim3(gx, 1), 256, 0, stream>>>(agg, wlb[l], hin, wrb[l], bl[l], hout, N, O);
        break;
      case 3:  // K=128, O=256: WC=2, 2 internal chunks (A fetched once)
        k_sage_gemm<2, 2, 2><<<dim3(gx, 1), 256, 0, stream>>>(agg, wlb[l], hin, wrb[l], bl[l], hout, N, O);
        break;
      default: // K=256, O=512: WC=2, 2 col-blocks x 2 internal chunks
        k_sage_gemm<2, 4, 2><<<dim3(gx, 2), 256, 0, stream>>>(agg, wlb[l], hin, wrb[l], bl[l], hout, N, O);
        break;
    }
    hin = hout;
  }
  k_out_softmax<<<idiv_up(N, 4), 256, 0, stream>>>(hin, Wout, bout, (float*)d_out, N);
}

// Round 9
// 507.473 us; speedup vs baseline: 1.1556x; 1.1556x over previous
//
#include <hip/hip_runtime.h>
#include <hip/hip_bf16.h>
#include <cstdint>
#include <cstddef>

// ---------------------------------------------------------------------------
// SAGE GNN forward, bf16 MFMA 32x32x16, LDS-staged GEMM, BK=64.
//  - round-6 schedule (wait0/barrier/stage(t+1)/compute; epilogue after loop)
//  - NEW: transposed grid (col-blocks dispatch-adjacent) -> A re-reads hit L3
//  - A tile [128][128B] XOR-swizzled; B pre-packed chunk-major
// ---------------------------------------------------------------------------

typedef short bf16x8 __attribute__((ext_vector_type(8)));   // 8 bf16 = 4 VGPRs
typedef float f32x16 __attribute__((ext_vector_type(16)));

static inline int idiv_up(int a, int b) { return (a + b - 1) / b; }

static __device__ __forceinline__ float bf2f(unsigned short u) {
  union { unsigned int i; float f; } v; v.i = ((unsigned int)u) << 16; return v.f;
}
static __device__ __forceinline__ unsigned short f2bf(float f) {
  union { float f; unsigned int i; } v; v.f = f;
  return (unsigned short)((v.i + 0x7FFFu + ((v.i >> 16) & 1u)) >> 16);  // RNE
}
static __device__ __forceinline__ float lo16(unsigned int u) { return bf2f((unsigned short)(u & 0xffffu)); }
static __device__ __forceinline__ float hi16(unsigned int u) { return bf2f((unsigned short)(u >> 16)); }
static __device__ __forceinline__ unsigned int packbf(float a, float b) {
  return (unsigned int)f2bf(a) | ((unsigned int)f2bf(b) << 16);
}

// async global->LDS, 16B per lane. LDS dest: wave-uniform base + lane*16.
static __device__ __forceinline__ void gl_lds16(const void* g, void* l) {
  typedef __attribute__((address_space(3))) unsigned int lds_u32;
  typedef __attribute__((address_space(1))) const unsigned int glb_u32;
  __builtin_amdgcn_global_load_lds((glb_u32*)(uintptr_t)g,
                                   (lds_u32*)(unsigned int)(uintptr_t)l, 16, 0, 0);
}

// ---------------- CSR build ----------------
__global__ void k_count_deg(const int* __restrict__ dst, int* __restrict__ deg, int E) {
  int e = blockIdx.x * blockDim.x + threadIdx.x;
  if (e < E) atomicAdd(deg + dst[e], 1);
}

// wave-shfl hierarchical scan, 1024 threads, chunked.
__global__ __launch_bounds__(1024)
void k_scan(const int* __restrict__ deg, int* __restrict__ row_off, int* __restrict__ cursor,
            float* __restrict__ deg_inv, int n) {
  __shared__ int wsum[16];
  const int tid = threadIdx.x;
  const int lane = tid & 63, wid = tid >> 6;
  int carry = 0;
  for (int base = 0; base < n; base += 1024) {
    const int i = base + tid;
    const int v = (i < n) ? deg[i] : 0;
    int incl = v;
#pragma unroll
    for (int off = 1; off < 64; off <<= 1) {
      int t = __shfl_up(incl, off);
      if (lane >= off) incl += t;
    }
    if (lane == 63) wsum[wid] = incl;
    __syncthreads();
    if (wid == 0) {
      int wv = (lane < 16) ? wsum[lane] : 0;
#pragma unroll
      for (int off = 1; off < 16; off <<= 1) {
        int t = __shfl_up(wv, off);
        if (lane >= off) wv += t;
      }
      if (lane < 16) wsum[lane] = wv;
    }
    __syncthreads();
    const int woff = (wid > 0) ? wsum[wid - 1] : 0;
    if (i < n) {
      const int ro = carry + woff + incl - v;
      row_off[i] = ro;
      cursor[i] = ro;
      deg_inv[i] = 1.0f / (float)((v > 1) ? v : 1);
    }
    const int tot = wsum[15];
    __syncthreads();
    carry += tot;
  }
  if (tid == 0) row_off[n] = carry;
}

__global__ void k_fill_csr(const int* __restrict__ src, const int* __restrict__ dst,
                           int* __restrict__ cursor, int* __restrict__ esrc, int E) {
  int e = blockIdx.x * blockDim.x + threadIdx.x;
  if (e < E) {
    int d = dst[e];
    int p = atomicAdd(cursor + d, 1);
    esrc[p] = src[e];
  }
}

// ---------------- x: f32 -> bf16 plain conversion --------------------------
__global__ __launch_bounds__(256)
void k_conv_x(const float* __restrict__ src, unsigned short* __restrict__ dst, int n4) {
  for (int i = blockIdx.x * blockDim.x + threadIdx.x; i < n4; i += gridDim.x * blockDim.x) {
    const float4 v = *((const float4*)src + i);
    uint2 o;
    o.x = packbf(v.x, v.y);
    o.y = packbf(v.z, v.w);
    *((uint2*)dst + i) = o;
  }
}

// ---------------- weights: f32 -> bf16 packed chunk-major ------------------
// dst elem index = kt64*(O*64) + chunk*(O*8) + col*8 + j  holds
// src[col][kt64*64 + chunk*8 + j]  (chunk in 0..7)
struct PackJob { const float* src; unsigned short* dst; int O; int K; };
struct PackJobs { PackJob j[10]; };

__global__ __launch_bounds__(256)
void k_pack_w(PackJobs jobs) {
  const PackJob J = jobs.j[blockIdx.y];
  const int total = J.O * J.K / 2;  // u32 outputs
  const int OK64 = J.O * 64;
  for (int u = blockIdx.x * blockDim.x + threadIdx.x; u < total; u += gridDim.x * blockDim.x) {
    const int e = u * 2;
    const int kt = e / OK64;
    const int rem = e - kt * OK64;
    const int chunk = rem / (J.O * 8);
    const int rem2 = rem - chunk * (J.O * 8);
    const int col = rem2 >> 3;
    const int j = rem2 & 7;
    const int korig = kt * 64 + chunk * 8 + j;
    const float f0 = J.src[(size_t)col * J.K + korig];
    const float f1 = J.src[(size_t)col * J.K + korig + 1];
    ((unsigned int*)J.dst)[u] = packbf(f0, f1);
  }
}

// ---------------- mean aggregation, bf16 in/out, f32 accum -----------------
__global__ __launch_bounds__(256)
void k_agg128(const unsigned short* __restrict__ h, const int* __restrict__ row_off,
              const int* __restrict__ esrc, const float* __restrict__ deg_inv,
              unsigned short* __restrict__ agg, int N) {
  const int node = blockIdx.x * 4 + (threadIdx.x >> 6);
  if (node >= N) return;
  const int lane = threadIdx.x & 63;
  const int s0 = row_off[node], s1 = row_off[node + 1];
  const unsigned int* hp = (const unsigned int*)h;
  float al = 0.f, ah = 0.f;
  int i = s0;
  for (; i + 8 <= s1; i += 8) {
    unsigned int u[8];
#pragma unroll
    for (int j = 0; j < 8; ++j) u[j] = hp[(size_t)esrc[i + j] * 64 + lane];
#pragma unroll
    for (int j = 0; j < 8; ++j) { al += lo16(u[j]); ah += hi16(u[j]); }
  }
  for (; i < s1; ++i) {
    const unsigned int u = hp[(size_t)esrc[i] * 64 + lane];
    al += lo16(u); ah += hi16(u);
  }
  const float di = deg_inv[node];
  ((unsigned int*)agg)[(size_t)node * 64 + lane] = packbf(al * di, ah * di);
}

__global__ __launch_bounds__(256)
void k_agg256(const unsigned short* __restrict__ h, const int* __restrict__ row_off,
              const int* __restrict__ esrc, const float* __restrict__ deg_inv,
              unsigned short* __restrict__ agg, int N) {
  const int node = blockIdx.x * 4 + (threadIdx.x >> 6);
  if (node >= N) return;
  const int lane = threadIdx.x & 63;
  const int s0 = row_off[node], s1 = row_off[node + 1];
  const unsigned int* hp = (const unsigned int*)h;
  float al = 0.f, ah = 0.f, bl_ = 0.f, bh = 0.f;
  int i = s0;
  for (; i + 4 <= s1; i += 4) {
    unsigned int u0[4], u1[4];
#pragma unroll
    for (int j = 0; j < 4; ++j) {
      const size_t b = (size_t)esrc[i + j] * 128;
      u0[j] = hp[b + lane];
      u1[j] = hp[b + 64 + lane];
    }
#pragma unroll
    for (int j = 0; j < 4; ++j) {
      al += lo16(u0[j]); ah += hi16(u0[j]);
      bl_ += lo16(u1[j]); bh += hi16(u1[j]);
    }
  }
  for (; i < s1; ++i) {
    const size_t b = (size_t)esrc[i] * 128;
    const unsigned int u0 = hp[b + lane];
    const unsigned int u1 = hp[b + 64 + lane];
    al += lo16(u0); ah += hi16(u0);
    bl_ += lo16(u1); bh += hi16(u1);
  }
  const float di = deg_inv[node];
  unsigned int* ap = (unsigned int*)agg;
  ap[(size_t)node * 128 + lane] = packbf(al * di, ah * di);
  ap[(size_t)node * 128 + 64 + lane] = packbf(bl_ * di, bh * di);
}

__global__ __launch_bounds__(256)
void k_agg64(const unsigned short* __restrict__ h, const int* __restrict__ row_off,
             const int* __restrict__ esrc, const float* __restrict__ deg_inv,
             unsigned short* __restrict__ agg, int N) {
  const int node = blockIdx.x * 4 + (threadIdx.x >> 6);
  if (node >= N) return;
  const int lane = threadIdx.x & 63;
  const int half = lane >> 5, c = lane & 31;
  const int s0 = row_off[node], s1 = row_off[node + 1];
  const unsigned int* hp = (const unsigned int*)h;
  float al = 0.f, ah = 0.f;
  int i = s0 + half;
  for (; i + 6 < s1; i += 8) {  // 4 edges per half per iter
    const unsigned int u0 = hp[(size_t)esrc[i] * 32 + c];
    const unsigned int u1 = hp[(size_t)esrc[i + 2] * 32 + c];
    const unsigned int u2 = hp[(size_t)esrc[i + 4] * 32 + c];
    const unsigned int u3 = hp[(size_t)esrc[i + 6] * 32 + c];
    al += lo16(u0) + lo16(u1) + lo16(u2) + lo16(u3);
    ah += hi16(u0) + hi16(u1) + hi16(u2) + hi16(u3);
  }
  for (; i < s1; i += 2) {
    const unsigned int u = hp[(size_t)esrc[i] * 32 + c];
    al += lo16(u); ah += hi16(u);
  }
  al += __shfl_xor(al, 32);
  ah += __shfl_xor(ah, 32);
  if (half == 0) {
    const float di = deg_inv[node];
    ((unsigned int*)agg)[(size_t)node * 32 + c] = packbf(al * di, ah * di);
  }
}

// ---------------- fused SAGE GEMM: C = relu(A0@B0p^T + A1@B1p^T + bias) ----
// Block: 128 rows x BN=WC*64 cols; 2 x WC waves; MFMA 32x32x16; BK=64.
// Grid: (col-blocks, row-panels) -- col-blocks sharing an A panel are
// dispatch-adjacent, so A re-reads hit L3 (FETCH counts HBM only).
// Round-6 schedule: wait vmcnt(0); barrier; stage(t+1); compute(t).
template <int WC>
__global__ __launch_bounds__(WC * 128)
void k_sage_gemm(const unsigned short* __restrict__ A0, const unsigned short* __restrict__ B0,
                 const unsigned short* __restrict__ A1, const unsigned short* __restrict__ B1,
                 const float* __restrict__ bias, unsigned short* __restrict__ C,
                 int Nn, int K, int O) {
  constexpr int BN = WC * 64;
  constexpr int T = WC * 128;
  constexpr int ACH = 1024;            // A 16B-chunks per tile (128 rows x 8)
  constexpr int BCH = BN * 8;          // B 16B-chunks per tile
  constexpr int LPT = (ACH + BCH) / T; // chunks per thread per stage
  constexpr int BSH = (WC == 1) ? 6 : ((WC == 2) ? 7 : 8);  // log2(BN)
  constexpr int LDSBUF = 16384 + BN * 128;
  __shared__ char lds[2 * LDSBUF];

  const int tid = threadIdx.x;
  const int w = tid >> 6, lane = tid & 63;
  const int wr = w / WC, wc = w % WC;
  const int fr = lane & 31, fq = lane >> 5;
  const int rowp = blockIdx.y;                 // row panel
  const int row0 = rowp * 128 + wr * 64;
  const int colb = blockIdx.x * BN;            // column block (fast index)

  const int KT0 = K >> 6;        // 64-wide tiles per phase
  const int NT = 2 * KT0;

  f32x16 acc[2][2];
#pragma unroll
  for (int m = 0; m < 2; ++m)
#pragma unroll
    for (int cn = 0; cn < 2; ++cn)
#pragma unroll
      for (int r = 0; r < 16; ++r) acc[m][cn][r] = 0.f;

  auto stage = [&](int buf, int t) {
    const int ph = (t >= KT0) ? 1 : 0;
    const unsigned short* Ab = ph ? A1 : A0;
    const unsigned short* Bb = ph ? B1 : B0;
    const int ktl = t - ph * KT0;
    char* lb = lds + buf * LDSBUF;
#pragma unroll
    for (int i = 0; i < LPT; ++i) {
      const int ch = tid + i * T;
      if (ch < ACH) {
        const int ar = ch >> 3, s = ch & 7;         // LDS row, slot
        int g = rowp * 128 + ar;
        if (g >= Nn) g = Nn - 1;
        // inverse-swizzled global source; linear LDS dest
        gl_lds16(Ab + (size_t)g * K + ktl * 64 + ((s ^ (ar & 7)) << 3), lb + ch * 16);
      } else {
        const int cb = ch - ACH;
        const int chunk = cb >> BSH, colrel = cb & (BN - 1);
        gl_lds16(Bb + (size_t)ktl * O * 64 + chunk * O * 8 + (colb + colrel) * 8,
                 lb + 16384 + cb * 16);
      }
    }
  };

  stage(0, 0);
#pragma unroll 1
  for (int t = 0; t < NT; ++t) {
    asm volatile("s_waitcnt vmcnt(0)" ::: "memory");
    __syncthreads();
    if (t + 1 < NT) stage((t + 1) & 1, t + 1);
    const char* lb = lds + (t & 1) * LDSBUF;
#pragma unroll
    for (int k16i = 0; k16i < 4; ++k16i) {
      const int c = k16i * 2 + fq;                  // chunk 0..7
      bf16x8 af[2], bg[2];
#pragma unroll
      for (int m = 0; m < 2; ++m) {
        const int rl = wr * 64 + m * 32 + fr;
        af[m] = *(const bf16x8*)(lb + rl * 128 + ((c ^ (rl & 7)) << 4));
      }
#pragma unroll
      for (int cn = 0; cn < 2; ++cn) {
        const int colrel = wc * 64 + cn * 32 + fr;
        bg[cn] = *(const bf16x8*)(lb + 16384 + c * (BN * 16) + colrel * 16);
      }
#pragma unroll
      for (int m = 0; m < 2; ++m)
#pragma unroll
        for (int cn = 0; cn < 2; ++cn)
          acc[m][cn] = __builtin_amdgcn_mfma_f32_32x32x16_bf16(af[m], bg[cn], acc[m][cn], 0, 0, 0);
    }
  }

  // epilogue. C/D map: col = lane&31, row = (reg&3) + 8*(reg>>2) + 4*(lane>>5).
#pragma unroll
  for (int cn = 0; cn < 2; ++cn) {
    const int col = colb + wc * 64 + cn * 32 + fr;
    const float bb = bias[col];
#pragma unroll
    for (int m = 0; m < 2; ++m) {
#pragma unroll
      for (int reg = 0; reg < 16; ++reg) {
        const float v = fmaxf(acc[m][cn][reg] + bb, 0.f);
        const float nb = __shfl_xor(v, 1);
        const int row = row0 + m * 32 + (reg & 3) + 8 * (reg >> 2) + 4 * fq;
        if (!(lane & 1) && row < Nn) {
          *(unsigned int*)(C + (size_t)row * O + col) = packbf(v, nb);
        }
      }
    }
  }
}

// ---------------- head: logits(512->4) + softmax, 4 waves per block --------
__global__ __launch_bounds__(256)
void k_out_softmax(const unsigned short* __restrict__ h, const float* __restrict__ W4,
                   const float* __restrict__ b, float* __restrict__ out, int N) {
  const int n = blockIdx.x * 4 + (threadIdx.x >> 6);
  if (n >= N) return;
  const int lane = threadIdx.x & 63;
  const unsigned int* hp = (const unsigned int*)h + (size_t)n * 256;
  float a[4] = {0.f, 0.f, 0.f, 0.f};
#pragma unroll
  for (int it = 0; it < 4; ++it) {
    const unsigned int v = hp[it * 64 + lane];
    const float lo = lo16(v);
    const float hi = hi16(v);
    const int k = (it * 64 + lane) * 2;
#pragma unroll
    for (int c = 0; c < 4; ++c)
      a[c] += lo * W4[c * 512 + k] + hi * W4[c * 512 + k + 1];
  }
#pragma unroll
  for (int off = 32; off > 0; off >>= 1) {
#pragma unroll
    for (int c = 0; c < 4; ++c) a[c] += __shfl_down(a[c], off);
  }
  if (lane == 0) {
    const float l0 = a[0] + b[0], l1 = a[1] + b[1], l2 = a[2] + b[2], l3 = a[3] + b[3];
    const float m = fmaxf(fmaxf(l0, l1), fmaxf(l2, l3));
    const float e0 = expf(l0 - m), e1 = expf(l1 - m), e2 = expf(l2 - m), e3 = expf(l3 - m);
    const float inv = 1.0f / (e0 + e1 + e2 + e3);
    float4 r; r.x = e0 * inv; r.y = e1 * inv; r.z = e2 * inv; r.w = e3 * inv;
    *(float4*)(out + (size_t)n * 4) = r;
  }
}

// ---------------------------------------------------------------------------
extern "C" void kernel_launch(void* const* d_in, const int* in_sizes, int n_in,
                              void* d_out, int out_size, void* d_ws, size_t ws_size,
                              hipStream_t stream) {
  const float* x = (const float*)d_in[0];
  const float* Wl[5] = {(const float*)d_in[1], (const float*)d_in[4], (const float*)d_in[7],
                        (const float*)d_in[10], (const float*)d_in[13]};
  const float* bl[5] = {(const float*)d_in[2], (const float*)d_in[5], (const float*)d_in[8],
                        (const float*)d_in[11], (const float*)d_in[14]};
  const float* Wr[5] = {(const float*)d_in[3], (const float*)d_in[6], (const float*)d_in[9],
                        (const float*)d_in[12], (const float*)d_in[15]};
  const float* Wout = (const float*)d_in[16];
  const float* bout = (const float*)d_in[17];
  const int* eidx = (const int*)d_in[18];

  const int N = in_sizes[0] / 128;
  const int E = in_sizes[18] / 2;
  const int* srcI = eidx;
  const int* dstI = eidx + E;

  const int Kd[5] = {128, 128, 64, 128, 256};
  const int Od[5] = {128, 64, 128, 256, 512};

  // workspace carve-out (256B aligned)
  char* ws = (char*)d_ws;
  size_t p = 0;
  auto alloc = [&](size_t bytes) { size_t r = p; p += (bytes + 255) & ~(size_t)255; return r; };
  int*   deg     = (int*)(ws + alloc((size_t)N * 4));
  int*   row_off = (int*)(ws + alloc((size_t)(N + 1) * 4));
  int*   cursor  = (int*)(ws + alloc((size_t)N * 4));
  float* deg_inv = (float*)(ws + alloc((size_t)N * 4));
  int*   esrc    = (int*)(ws + alloc((size_t)E * 4));
  unsigned short* xb = (unsigned short*)(ws + alloc((size_t)N * 128 * 2));
  unsigned short* wlb[5];
  unsigned short* wrb[5];
  for (int l = 0; l < 5; ++l) {
    wlb[l] = (unsigned short*)(ws + alloc((size_t)Od[l] * Kd[l] * 2));
    wrb[l] = (unsigned short*)(ws + alloc((size_t)Od[l] * Kd[l] * 2));
  }
  unsigned short* bufA = (unsigned short*)(ws + alloc((size_t)N * 512 * 2));
  unsigned short* bufB = (unsigned short*)(ws + alloc((size_t)N * 256 * 2));
  unsigned short* agg  = (unsigned short*)(ws + alloc((size_t)N * 256 * 2));
  (void)ws_size; (void)n_in; (void)out_size;

  // ---- conversions: x plain; weights packed chunk-major ----
  k_conv_x<<<128, 256, 0, stream>>>(x, xb, N * 128 / 4);
  PackJobs jobs;
  for (int l = 0; l < 5; ++l) {
    jobs.j[2 * l]     = {Wl[l], wlb[l], Od[l], Kd[l]};
    jobs.j[2 * l + 1] = {Wr[l], wrb[l], Od[l], Kd[l]};
  }
  k_pack_w<<<dim3(32, 10), 256, 0, stream>>>(jobs);

  // ---- CSR build ----
  hipMemsetAsync(deg, 0, (size_t)N * 4, stream);
  k_count_deg<<<idiv_up(E, 256), 256, 0, stream>>>(dstI, deg, E);
  k_scan<<<1, 1024, 0, stream>>>(deg, row_off, cursor, deg_inv, N);
  k_fill_csr<<<idiv_up(E, 256), 256, 0, stream>>>(srcI, dstI, cursor, esrc, E);

  unsigned short* houts[5] = {bufA, bufB, bufA, bufB, bufA};

  const unsigned short* hin = xb;
  const int gx = idiv_up(N, 128);
  for (int l = 0; l < 5; ++l) {
    const int K = Kd[l], O = Od[l];
    // aggregate
    if (K == 64)
      k_agg64<<<idiv_up(N, 4), 256, 0, stream>>>(hin, row_off, esrc, deg_inv, agg, N);
    else if (K == 128)
      k_agg128<<<idiv_up(N, 4), 256, 0, stream>>>(hin, row_off, esrc, deg_inv, agg, N);
    else
      k_agg256<<<idiv_up(N, 4), 256, 0, stream>>>(hin, row_off, esrc, deg_inv, agg, N);

    // fused GEMM + bias + relu (grid = (col-blocks, row-panels))
    unsigned short* hout = houts[l];
    switch (l) {
      case 0:  // K=128, O=128: WC=2, 1 col-block
        k_sage_gemm<2><<<dim3(1, gx), 256, 0, stream>>>(agg, wlb[l], hin, wrb[l], bl[l], hout, N, K, O);
        break;
      case 1:  // K=128, O=64: WC=1, 1 col-block
        k_sage_gemm<1><<<dim3(1, gx), 128, 0, stream>>>(agg, wlb[l], hin, wrb[l], bl[l], hout, N, K, O);
        break;
      case 2:  // K=64, O=128: WC=2, 1 col-block
        k_sage_gemm<2><<<dim3(1, gx), 256, 0, stream>>>(agg, wlb[l], hin, wrb[l], bl[l], hout, N, K, O);
        break;
      case 3:  // K=128, O=256: WC=2, 2 col-blocks (dispatch-adjacent)
        k_sage_gemm<2><<<dim3(2, gx), 256, 0, stream>>>(agg, wlb[l], hin, wrb[l], bl[l], hout, N, K, O);
        break;
      default: // K=256, O=512: WC=2, 4 col-blocks (dispatch-adjacent)
        k_sage_gemm<2><<<dim3(4, gx), 256, 0, stream>>>(agg, wlb[l], hin, wrb[l], bl[l], hout, N, K, O);
        break;
    }
    hin = hout;
  }
  k_out_softmax<<<idiv_up(N, 4), 256, 0, stream>>>(hin, Wout, bout, (float*)d_out, N);
}

// Round 10
// 465.349 us; speedup vs baseline: 1.2602x; 1.0905x over previous
//
#include <hip/hip_runtime.h>
#include <hip/hip_bf16.h>
#include <cstdint>
#include <cstddef>

// ---------------------------------------------------------------------------
// SAGE GNN forward, bf16 MFMA 32x32x16, LDS-staged GEMM, BK=64.
//  - GEMM: round-6 schedule, transposed grid (round 9) -- best known
//  - NEW aggregates: uint4 (16B) lanes, 16 edges/batch via shfl-broadcast
//    edge ids -> 4-8x fewer load instructions, 16 rows in flight per wave
// ---------------------------------------------------------------------------

typedef short bf16x8 __attribute__((ext_vector_type(8)));   // 8 bf16 = 4 VGPRs
typedef float f32x16 __attribute__((ext_vector_type(16)));

static inline int idiv_up(int a, int b) { return (a + b - 1) / b; }

static __device__ __forceinline__ float bf2f(unsigned short u) {
  union { unsigned int i; float f; } v; v.i = ((unsigned int)u) << 16; return v.f;
}
static __device__ __forceinline__ unsigned short f2bf(float f) {
  union { float f; unsigned int i; } v; v.f = f;
  return (unsigned short)((v.i + 0x7FFFu + ((v.i >> 16) & 1u)) >> 16);  // RNE
}
static __device__ __forceinline__ float lo16(unsigned int u) { return bf2f((unsigned short)(u & 0xffffu)); }
static __device__ __forceinline__ float hi16(unsigned int u) { return bf2f((unsigned short)(u >> 16)); }
static __device__ __forceinline__ unsigned int packbf(float a, float b) {
  return (unsigned int)f2bf(a) | ((unsigned int)f2bf(b) << 16);
}

// async global->LDS, 16B per lane. LDS dest: wave-uniform base + lane*16.
static __device__ __forceinline__ void gl_lds16(const void* g, void* l) {
  typedef __attribute__((address_space(3))) unsigned int lds_u32;
  typedef __attribute__((address_space(1))) const unsigned int glb_u32;
  __builtin_amdgcn_global_load_lds((glb_u32*)(uintptr_t)g,
                                   (lds_u32*)(unsigned int)(uintptr_t)l, 16, 0, 0);
}

// ---------------- CSR build ----------------
__global__ void k_count_deg(const int* __restrict__ dst, int* __restrict__ deg, int E) {
  int e = blockIdx.x * blockDim.x + threadIdx.x;
  if (e < E) atomicAdd(deg + dst[e], 1);
}

// wave-shfl hierarchical scan, 1024 threads, chunked.
__global__ __launch_bounds__(1024)
void k_scan(const int* __restrict__ deg, int* __restrict__ row_off, int* __restrict__ cursor,
            float* __restrict__ deg_inv, int n) {
  __shared__ int wsum[16];
  const int tid = threadIdx.x;
  const int lane = tid & 63, wid = tid >> 6;
  int carry = 0;
  for (int base = 0; base < n; base += 1024) {
    const int i = base + tid;
    const int v = (i < n) ? deg[i] : 0;
    int incl = v;
#pragma unroll
    for (int off = 1; off < 64; off <<= 1) {
      int t = __shfl_up(incl, off);
      if (lane >= off) incl += t;
    }
    if (lane == 63) wsum[wid] = incl;
    __syncthreads();
    if (wid == 0) {
      int wv = (lane < 16) ? wsum[lane] : 0;
#pragma unroll
      for (int off = 1; off < 16; off <<= 1) {
        int t = __shfl_up(wv, off);
        if (lane >= off) wv += t;
      }
      if (lane < 16) wsum[lane] = wv;
    }
    __syncthreads();
    const int woff = (wid > 0) ? wsum[wid - 1] : 0;
    if (i < n) {
      const int ro = carry + woff + incl - v;
      row_off[i] = ro;
      cursor[i] = ro;
      deg_inv[i] = 1.0f / (float)((v > 1) ? v : 1);
    }
    const int tot = wsum[15];
    __syncthreads();
    carry += tot;
  }
  if (tid == 0) row_off[n] = carry;
}

__global__ void k_fill_csr(const int* __restrict__ src, const int* __restrict__ dst,
                           int* __restrict__ cursor, int* __restrict__ esrc, int E) {
  int e = blockIdx.x * blockDim.x + threadIdx.x;
  if (e < E) {
    int d = dst[e];
    int p = atomicAdd(cursor + d, 1);
    esrc[p] = src[e];
  }
}

// ---------------- x: f32 -> bf16 plain conversion --------------------------
__global__ __launch_bounds__(256)
void k_conv_x(const float* __restrict__ src, unsigned short* __restrict__ dst, int n4) {
  for (int i = blockIdx.x * blockDim.x + threadIdx.x; i < n4; i += gridDim.x * blockDim.x) {
    const float4 v = *((const float4*)src + i);
    uint2 o;
    o.x = packbf(v.x, v.y);
    o.y = packbf(v.z, v.w);
    *((uint2*)dst + i) = o;
  }
}

// ---------------- weights: f32 -> bf16 packed chunk-major ------------------
// dst elem index = kt64*(O*64) + chunk*(O*8) + col*8 + j  holds
// src[col][kt64*64 + chunk*8 + j]  (chunk in 0..7)
struct PackJob { const float* src; unsigned short* dst; int O; int K; };
struct PackJobs { PackJob j[10]; };

__global__ __launch_bounds__(256)
void k_pack_w(PackJobs jobs) {
  const PackJob J = jobs.j[blockIdx.y];
  const int total = J.O * J.K / 2;  // u32 outputs
  const int OK64 = J.O * 64;
  for (int u = blockIdx.x * blockDim.x + threadIdx.x; u < total; u += gridDim.x * blockDim.x) {
    const int e = u * 2;
    const int kt = e / OK64;
    const int rem = e - kt * OK64;
    const int chunk = rem / (J.O * 8);
    const int rem2 = rem - chunk * (J.O * 8);
    const int col = rem2 >> 3;
    const int j = rem2 & 7;
    const int korig = kt * 64 + chunk * 8 + j;
    const float f0 = J.src[(size_t)col * J.K + korig];
    const float f1 = J.src[(size_t)col * J.K + korig + 1];
    ((unsigned int*)J.dst)[u] = packbf(f0, f1);
  }
}

// ---------------- mean aggregation, bf16 in/out, f32 accum -----------------
// One wave per node; lanes load uint4 (16B). Subgroup of G lanes covers one
// row; 64/G edges per load instruction; batch of 16 edges per iteration with
// edge ids broadcast from a single esrc vector load via __shfl.
static __device__ __forceinline__ void acc_u4(float* acc, const uint4& v) {
  acc[0] += lo16(v.x); acc[1] += hi16(v.x);
  acc[2] += lo16(v.y); acc[3] += hi16(v.y);
  acc[4] += lo16(v.z); acc[5] += hi16(v.z);
  acc[6] += lo16(v.w); acc[7] += hi16(v.w);
}

// K=128: row = 16 uint4; 4 subgroups of 16 lanes; 4 edges per load instr.
__global__ __launch_bounds__(256)
void k_agg128(const unsigned short* __restrict__ h, const int* __restrict__ row_off,
              const int* __restrict__ esrc, const float* __restrict__ deg_inv,
              unsigned short* __restrict__ agg, int N) {
  const int node = blockIdx.x * 4 + (threadIdx.x >> 6);
  if (node >= N) return;
  const int lane = threadIdx.x & 63;
  const int g = lane >> 4, c = lane & 15;
  const int s0 = row_off[node], s1 = row_off[node + 1];
  const uint4* hp = (const uint4*)h;
  float acc[8] = {0.f, 0.f, 0.f, 0.f, 0.f, 0.f, 0.f, 0.f};
  for (int i = s0; i < s1; i += 16) {
    int el = i + (lane & 15);
    if (el >= s1) el = s1 - 1;
    const int ev = esrc[el];
    uint4 v[4];
#pragma unroll
    for (int u = 0; u < 4; ++u) {
      if (i + u * 4 < s1) {                      // wave-uniform
        const int e = __shfl(ev, u * 4 + g);
        v[u] = hp[(size_t)e * 16 + c];
      }
    }
#pragma unroll
    for (int u = 0; u < 4; ++u)
      if (i + u * 4 + g < s1) acc_u4(acc, v[u]);
  }
#pragma unroll
  for (int j = 0; j < 8; ++j) {
    acc[j] += __shfl_xor(acc[j], 16);
    acc[j] += __shfl_xor(acc[j], 32);
  }
  if (g == 0) {
    const float di = deg_inv[node];
    uint4 o;
    o.x = packbf(acc[0] * di, acc[1] * di);
    o.y = packbf(acc[2] * di, acc[3] * di);
    o.z = packbf(acc[4] * di, acc[5] * di);
    o.w = packbf(acc[6] * di, acc[7] * di);
    ((uint4*)agg)[(size_t)node * 16 + c] = o;
  }
}

// K=256: row = 32 uint4; 2 subgroups of 32 lanes; 2 edges per load instr.
__global__ __launch_bounds__(256)
void k_agg256(const unsigned short* __restrict__ h, const int* __restrict__ row_off,
              const int* __restrict__ esrc, const float* __restrict__ deg_inv,
              unsigned short* __restrict__ agg, int N) {
  const int node = blockIdx.x * 4 + (threadIdx.x >> 6);
  if (node >= N) return;
  const int lane = threadIdx.x & 63;
  const int g = lane >> 5, c = lane & 31;
  const int s0 = row_off[node], s1 = row_off[node + 1];
  const uint4* hp = (const uint4*)h;
  float acc[8] = {0.f, 0.f, 0.f, 0.f, 0.f, 0.f, 0.f, 0.f};
  for (int i = s0; i < s1; i += 16) {
    int el = i + (lane & 15);
    if (el >= s1) el = s1 - 1;
    const int ev = esrc[el];
    uint4 v[8];
#pragma unroll
    for (int u = 0; u < 8; ++u) {
      if (i + u * 2 < s1) {                      // wave-uniform
        const int e = __shfl(ev, u * 2 + g);
        v[u] = hp[(size_t)e * 32 + c];
      }
    }
#pragma unroll
    for (int u = 0; u < 8; ++u)
      if (i + u * 2 + g < s1) acc_u4(acc, v[u]);
  }
#pragma unroll
  for (int j = 0; j < 8; ++j) acc[j] += __shfl_xor(acc[j], 32);
  if (g == 0) {
    const float di = deg_inv[node];
    uint4 o;
    o.x = packbf(acc[0] * di, acc[1] * di);
    o.y = packbf(acc[2] * di, acc[3] * di);
    o.z = packbf(acc[4] * di, acc[5] * di);
    o.w = packbf(acc[6] * di, acc[7] * di);
    ((uint4*)agg)[(size_t)node * 32 + c] = o;
  }
}

// K=64: row = 8 uint4; 8 subgroups of 8 lanes; 8 edges per load instr.
__global__ __launch_bounds__(256)
void k_agg64(const unsigned short* __restrict__ h, const int* __restrict__ row_off,
             const int* __restrict__ esrc, const float* __restrict__ deg_inv,
             unsigned short* __restrict__ agg, int N) {
  const int node = blockIdx.x * 4 + (threadIdx.x >> 6);
  if (node >= N) return;
  const int lane = threadIdx.x & 63;
  const int g = lane >> 3, c = lane & 7;
  const int s0 = row_off[node], s1 = row_off[node + 1];
  const uint4* hp = (const uint4*)h;
  float acc[8] = {0.f, 0.f, 0.f, 0.f, 0.f, 0.f, 0.f, 0.f};
  for (int i = s0; i < s1; i += 16) {
    int el = i + (lane & 15);
    if (el >= s1) el = s1 - 1;
    const int ev = esrc[el];
    uint4 v[2];
#pragma unroll
    for (int u = 0; u < 2; ++u) {
      if (i + u * 8 < s1) {                      // wave-uniform
        const int e = __shfl(ev, u * 8 + g);
        v[u] = hp[(size_t)e * 8 + c];
      }
    }
#pragma unroll
    for (int u = 0; u < 2; ++u)
      if (i + u * 8 + g < s1) acc_u4(acc, v[u]);
  }
#pragma unroll
  for (int j = 0; j < 8; ++j) {
    acc[j] += __shfl_xor(acc[j], 8);
    acc[j] += __shfl_xor(acc[j], 16);
    acc[j] += __shfl_xor(acc[j], 32);
  }
  if (g == 0) {
    const float di = deg_inv[node];
    uint4 o;
    o.x = packbf(acc[0] * di, acc[1] * di);
    o.y = packbf(acc[2] * di, acc[3] * di);
    o.z = packbf(acc[4] * di, acc[5] * di);
    o.w = packbf(acc[6] * di, acc[7] * di);
    ((uint4*)agg)[(size_t)node * 8 + c] = o;
  }
}

// ---------------- fused SAGE GEMM: C = relu(A0@B0p^T + A1@B1p^T + bias) ----
// Block: 128 rows x BN=WC*64 cols; 2 x WC waves; MFMA 32x32x16; BK=64.
// Grid: (col-blocks, row-panels). Round-6 schedule.
template <int WC>
__global__ __launch_bounds__(WC * 128)
void k_sage_gemm(const unsigned short* __restrict__ A0, const unsigned short* __restrict__ B0,
                 const unsigned short* __restrict__ A1, const unsigned short* __restrict__ B1,
                 const float* __restrict__ bias, unsigned short* __restrict__ C,
                 int Nn, int K, int O) {
  constexpr int BN = WC * 64;
  constexpr int T = WC * 128;
  constexpr int ACH = 1024;            // A 16B-chunks per tile (128 rows x 8)
  constexpr int BCH = BN * 8;          // B 16B-chunks per tile
  constexpr int LPT = (ACH + BCH) / T; // chunks per thread per stage
  constexpr int BSH = (WC == 1) ? 6 : ((WC == 2) ? 7 : 8);  // log2(BN)
  constexpr int LDSBUF = 16384 + BN * 128;
  __shared__ char lds[2 * LDSBUF];

  const int tid = threadIdx.x;
  const int w = tid >> 6, lane = tid & 63;
  const int wr = w / WC, wc = w % WC;
  const int fr = lane & 31, fq = lane >> 5;
  const int rowp = blockIdx.y;                 // row panel
  const int row0 = rowp * 128 + wr * 64;
  const int colb = blockIdx.x * BN;            // column block (fast index)

  const int KT0 = K >> 6;        // 64-wide tiles per phase
  const int NT = 2 * KT0;

  f32x16 acc[2][2];
#pragma unroll
  for (int m = 0; m < 2; ++m)
#pragma unroll
    for (int cn = 0; cn < 2; ++cn)
#pragma unroll
      for (int r = 0; r < 16; ++r) acc[m][cn][r] = 0.f;

  auto stage = [&](int buf, int t) {
    const int ph = (t >= KT0) ? 1 : 0;
    const unsigned short* Ab = ph ? A1 : A0;
    const unsigned short* Bb = ph ? B1 : B0;
    const int ktl = t - ph * KT0;
    char* lb = lds + buf * LDSBUF;
#pragma unroll
    for (int i = 0; i < LPT; ++i) {
      const int ch = tid + i * T;
      if (ch < ACH) {
        const int ar = ch >> 3, s = ch & 7;         // LDS row, slot
        int g = rowp * 128 + ar;
        if (g >= Nn) g = Nn - 1;
        // inverse-swizzled global source; linear LDS dest
        gl_lds16(Ab + (size_t)g * K + ktl * 64 + ((s ^ (ar & 7)) << 3), lb + ch * 16);
      } else {
        const int cb = ch - ACH;
        const int chunk = cb >> BSH, colrel = cb & (BN - 1);
        gl_lds16(Bb + (size_t)ktl * O * 64 + chunk * O * 8 + (colb + colrel) * 8,
                 lb + 16384 + cb * 16);
      }
    }
  };

  stage(0, 0);
#pragma unroll 1
  for (int t = 0; t < NT; ++t) {
    asm volatile("s_waitcnt vmcnt(0)" ::: "memory");
    __syncthreads();
    if (t + 1 < NT) stage((t + 1) & 1, t + 1);
    const char* lb = lds + (t & 1) * LDSBUF;
#pragma unroll
    for (int k16i = 0; k16i < 4; ++k16i) {
      const int c = k16i * 2 + fq;                  // chunk 0..7
      bf16x8 af[2], bg[2];
#pragma unroll
      for (int m = 0; m < 2; ++m) {
        const int rl = wr * 64 + m * 32 + fr;
        af[m] = *(const bf16x8*)(lb + rl * 128 + ((c ^ (rl & 7)) << 4));
      }
#pragma unroll
      for (int cn = 0; cn < 2; ++cn) {
        const int colrel = wc * 64 + cn * 32 + fr;
        bg[cn] = *(const bf16x8*)(lb + 16384 + c * (BN * 16) + colrel * 16);
      }
#pragma unroll
      for (int m = 0; m < 2; ++m)
#pragma unroll
        for (int cn = 0; cn < 2; ++cn)
          acc[m][cn] = __builtin_amdgcn_mfma_f32_32x32x16_bf16(af[m], bg[cn], acc[m][cn], 0, 0, 0);
    }
  }

  // epilogue. C/D map: col = lane&31, row = (reg&3) + 8*(reg>>2) + 4*(lane>>5).
#pragma unroll
  for (int cn = 0; cn < 2; ++cn) {
    const int col = colb + wc * 64 + cn * 32 + fr;
    const float bb = bias[col];
#pragma unroll
    for (int m = 0; m < 2; ++m) {
#pragma unroll
      for (int reg = 0; reg < 16; ++reg) {
        const float v = fmaxf(acc[m][cn][reg] + bb, 0.f);
        const float nb = __shfl_xor(v, 1);
        const int row = row0 + m * 32 + (reg & 3) + 8 * (reg >> 2) + 4 * fq;
        if (!(lane & 1) && row < Nn) {
          *(unsigned int*)(C + (size_t)row * O + col) = packbf(v, nb);
        }
      }
    }
  }
}

// ---------------- head: logits(512->4) + softmax, 4 waves per block --------
__global__ __launch_bounds__(256)
void k_out_softmax(const unsigned short* __restrict__ h, const float* __restrict__ W4,
                   const float* __restrict__ b, float* __restrict__ out, int N) {
  const int n = blockIdx.x * 4 + (threadIdx.x >> 6);
  if (n >= N) return;
  const int lane = threadIdx.x & 63;
  const unsigned int* hp = (const unsigned int*)h + (size_t)n * 256;
  float a[4] = {0.f, 0.f, 0.f, 0.f};
#pragma unroll
  for (int it = 0; it < 4; ++it) {
    const unsigned int v = hp[it * 64 + lane];
    const float lo = lo16(v);
    const float hi = hi16(v);
    const int k = (it * 64 + lane) * 2;
#pragma unroll
    for (int c = 0; c < 4; ++c)
      a[c] += lo * W4[c * 512 + k] + hi * W4[c * 512 + k + 1];
  }
#pragma unroll
  for (int off = 32; off > 0; off >>= 1) {
#pragma unroll
    for (int c = 0; c < 4; ++c) a[c] += __shfl_down(a[c], off);
  }
  if (lane == 0) {
    const float l0 = a[0] + b[0], l1 = a[1] + b[1], l2 = a[2] + b[2], l3 = a[3] + b[3];
    const float m = fmaxf(fmaxf(l0, l1), fmaxf(l2, l3));
    const float e0 = expf(l0 - m), e1 = expf(l1 - m), e2 = expf(l2 - m), e3 = expf(l3 - m);
    const float inv = 1.0f / (e0 + e1 + e2 + e3);
    float4 r; r.x = e0 * inv; r.y = e1 * inv; r.z = e2 * inv; r.w = e3 * inv;
    *(float4*)(out + (size_t)n * 4) = r;
  }
}

// ---------------------------------------------------------------------------
extern "C" void kernel_launch(void* const* d_in, const int* in_sizes, int n_in,
                              void* d_out, int out_size, void* d_ws, size_t ws_size,
                              hipStream_t stream) {
  const float* x = (const float*)d_in[0];
  const float* Wl[5] = {(const float*)d_in[1], (const float*)d_in[4], (const float*)d_in[7],
                        (const float*)d_in[10], (const float*)d_in[13]};
  const float* bl[5] = {(const float*)d_in[2], (const float*)d_in[5], (const float*)d_in[8],
                        (const float*)d_in[11], (const float*)d_in[14]};
  const float* Wr[5] = {(const float*)d_in[3], (const float*)d_in[6], (const float*)d_in[9],
                        (const float*)d_in[12], (const float*)d_in[15]};
  const float* Wout = (const float*)d_in[16];
  const float* bout = (const float*)d_in[17];
  const int* eidx = (const int*)d_in[18];

  const int N = in_sizes[0] / 128;
  const int E = in_sizes[18] / 2;
  const int* srcI = eidx;
  const int* dstI = eidx + E;

  const int Kd[5] = {128, 128, 64, 128, 256};
  const int Od[5] = {128, 64, 128, 256, 512};

  // workspace carve-out (256B aligned)
  char* ws = (char*)d_ws;
  size_t p = 0;
  auto alloc = [&](size_t bytes) { size_t r = p; p += (bytes + 255) & ~(size_t)255; return r; };
  int*   deg     = (int*)(ws + alloc((size_t)N * 4));
  int*   row_off = (int*)(ws + alloc((size_t)(N + 1) * 4));
  int*   cursor  = (int*)(ws + alloc((size_t)N * 4));
  float* deg_inv = (float*)(ws + alloc((size_t)N * 4));
  int*   esrc    = (int*)(ws + alloc((size_t)E * 4));
  unsigned short* xb = (unsigned short*)(ws + alloc((size_t)N * 128 * 2));
  unsigned short* wlb[5];
  unsigned short* wrb[5];
  for (int l = 0; l < 5; ++l) {
    wlb[l] = (unsigned short*)(ws + alloc((size_t)Od[l] * Kd[l] * 2));
    wrb[l] = (unsigned short*)(ws + alloc((size_t)Od[l] * Kd[l] * 2));
  }
  unsigned short* bufA = (unsigned short*)(ws + alloc((size_t)N * 512 * 2));
  unsigned short* bufB = (unsigned short*)(ws + alloc((size_t)N * 256 * 2));
  unsigned short* agg  = (unsigned short*)(ws + alloc((size_t)N * 256 * 2));
  (void)ws_size; (void)n_in; (void)out_size;

  // ---- conversions: x plain; weights packed chunk-major ----
  k_conv_x<<<128, 256, 0, stream>>>(x, xb, N * 128 / 4);
  PackJobs jobs;
  for (int l = 0; l < 5; ++l) {
    jobs.j[2 * l]     = {Wl[l], wlb[l], Od[l], Kd[l]};
    jobs.j[2 * l + 1] = {Wr[l], wrb[l], Od[l], Kd[l]};
  }
  k_pack_w<<<dim3(32, 10), 256, 0, stream>>>(jobs);

  // ---- CSR build ----
  hipMemsetAsync(deg, 0, (size_t)N * 4, stream);
  k_count_deg<<<idiv_up(E, 256), 256, 0, stream>>>(dstI, deg, E);
  k_scan<<<1, 1024, 0, stream>>>(deg, row_off, cursor, deg_inv, N);
  k_fill_csr<<<idiv_up(E, 256), 256, 0, stream>>>(srcI, dstI, cursor, esrc, E);

  unsigned short* houts[5] = {bufA, bufB, bufA, bufB, bufA};

  const unsigned short* hin = xb;
  const int gx = idiv_up(N, 128);
  for (int l = 0; l < 5; ++l) {
    const int K = Kd[l], O = Od[l];
    // aggregate
    if (K == 64)
      k_agg64<<<idiv_up(N, 4), 256, 0, stream>>>(hin, row_off, esrc, deg_inv, agg, N);
    else if (K == 128)
      k_agg128<<<idiv_up(N, 4), 256, 0, stream>>>(hin, row_off, esrc, deg_inv, agg, N);
    else
      k_agg256<<<idiv_up(N, 4), 256, 0, stream>>>(hin, row_off, esrc, deg_inv, agg, N);

    // fused GEMM + bias + relu (grid = (col-blocks, row-panels))
    unsigned short* hout = houts[l];
    switch (l) {
      case 0:  // K=128, O=128: WC=2, 1 col-block
        k_sage_gemm<2><<<dim3(1, gx), 256, 0, stream>>>(agg, wlb[l], hin, wrb[l], bl[l], hout, N, K, O);
        break;
      case 1:  // K=128, O=64: WC=1, 1 col-block
        k_sage_gemm<1><<<dim3(1, gx), 128, 0, stream>>>(agg, wlb[l], hin, wrb[l], bl[l], hout, N, K, O);
        break;
      case 2:  // K=64, O=128: WC=2, 1 col-block
        k_sage_gemm<2><<<dim3(1, gx), 256, 0, stream>>>(agg, wlb[l], hin, wrb[l], bl[l], hout, N, K, O);
        break;
      case 3:  // K=128, O=256: WC=2, 2 col-blocks (dispatch-adjacent)
        k_sage_gemm<2><<<dim3(2, gx), 256, 0, stream>>>(agg, wlb[l], hin, wrb[l], bl[l], hout, N, K, O);
        break;
      default: // K=256, O=512: WC=2, 4 col-blocks (dispatch-adjacent)
        k_sage_gemm<2><<<dim3(4, gx), 256, 0, stream>>>(agg, wlb[l], hin, wrb[l], bl[l], hout, N, K, O);
        break;
    }
    hin = hout;
  }
  k_out_softmax<<<idiv_up(N, 4), 256, 0, stream>>>(hin, Wout, bout, (float*)d_out, N);
}

// Round 11
// 461.888 us; speedup vs baseline: 1.2696x; 1.0075x over previous
//
#include <hip/hip_runtime.h>
#include <hip/hip_bf16.h>
#include <cstdint>
#include <cstddef>

// ---------------------------------------------------------------------------
// SAGE GNN forward, bf16 MFMA 32x32x16, LDS-staged GEMM, BK=64.
//  - GEMM: round-6 schedule + XCD-co-located col-blocks (same-XCD A reuse)
//  - L1: linearity swap -- raw GEMM h1@[Wl;Wr]^T, then 64-wide fused aggregate
//  - aggregates: uint4 lanes, 16-edge shfl-broadcast batches (round 10)
// ---------------------------------------------------------------------------

typedef short bf16x8 __attribute__((ext_vector_type(8)));   // 8 bf16 = 4 VGPRs
typedef float f32x16 __attribute__((ext_vector_type(16)));

static inline int idiv_up(int a, int b) { return (a + b - 1) / b; }

static __device__ __forceinline__ float bf2f(unsigned short u) {
  union { unsigned int i; float f; } v; v.i = ((unsigned int)u) << 16; return v.f;
}
static __device__ __forceinline__ unsigned short f2bf(float f) {
  union { float f; unsigned int i; } v; v.f = f;
  return (unsigned short)((v.i + 0x7FFFu + ((v.i >> 16) & 1u)) >> 16);  // RNE
}
static __device__ __forceinline__ float lo16(unsigned int u) { return bf2f((unsigned short)(u & 0xffffu)); }
static __device__ __forceinline__ float hi16(unsigned int u) { return bf2f((unsigned short)(u >> 16)); }
static __device__ __forceinline__ unsigned int packbf(float a, float b) {
  return (unsigned int)f2bf(a) | ((unsigned int)f2bf(b) << 16);
}

// async global->LDS, 16B per lane. LDS dest: wave-uniform base + lane*16.
static __device__ __forceinline__ void gl_lds16(const void* g, void* l) {
  typedef __attribute__((address_space(3))) unsigned int lds_u32;
  typedef __attribute__((address_space(1))) const unsigned int glb_u32;
  __builtin_amdgcn_global_load_lds((glb_u32*)(uintptr_t)g,
                                   (lds_u32*)(unsigned int)(uintptr_t)l, 16, 0, 0);
}

// ---------------- CSR build ----------------
__global__ void k_count_deg(const int* __restrict__ dst, int* __restrict__ deg, int E) {
  int e = blockIdx.x * blockDim.x + threadIdx.x;
  if (e < E) atomicAdd(deg + dst[e], 1);
}

// wave-shfl hierarchical scan, 1024 threads, chunked.
__global__ __launch_bounds__(1024)
void k_scan(const int* __restrict__ deg, int* __restrict__ row_off, int* __restrict__ cursor,
            float* __restrict__ deg_inv, int n) {
  __shared__ int wsum[16];
  const int tid = threadIdx.x;
  const int lane = tid & 63, wid = tid >> 6;
  int carry = 0;
  for (int base = 0; base < n; base += 1024) {
    const int i = base + tid;
    const int v = (i < n) ? deg[i] : 0;
    int incl = v;
#pragma unroll
    for (int off = 1; off < 64; off <<= 1) {
      int t = __shfl_up(incl, off);
      if (lane >= off) incl += t;
    }
    if (lane == 63) wsum[wid] = incl;
    __syncthreads();
    if (wid == 0) {
      int wv = (lane < 16) ? wsum[lane] : 0;
#pragma unroll
      for (int off = 1; off < 16; off <<= 1) {
        int t = __shfl_up(wv, off);
        if (lane >= off) wv += t;
      }
      if (lane < 16) wsum[lane] = wv;
    }
    __syncthreads();
    const int woff = (wid > 0) ? wsum[wid - 1] : 0;
    if (i < n) {
      const int ro = carry + woff + incl - v;
      row_off[i] = ro;
      cursor[i] = ro;
      deg_inv[i] = 1.0f / (float)((v > 1) ? v : 1);
    }
    const int tot = wsum[15];
    __syncthreads();
    carry += tot;
  }
  if (tid == 0) row_off[n] = carry;
}

__global__ void k_fill_csr(const int* __restrict__ src, const int* __restrict__ dst,
                           int* __restrict__ cursor, int* __restrict__ esrc, int E) {
  int e = blockIdx.x * blockDim.x + threadIdx.x;
  if (e < E) {
    int d = dst[e];
    int p = atomicAdd(cursor + d, 1);
    esrc[p] = src[e];
  }
}

// ---------------- x: f32 -> bf16 plain conversion --------------------------
__global__ __launch_bounds__(256)
void k_conv_x(const float* __restrict__ src, unsigned short* __restrict__ dst, int n4) {
  for (int i = blockIdx.x * blockDim.x + threadIdx.x; i < n4; i += gridDim.x * blockDim.x) {
    const float4 v = *((const float4*)src + i);
    uint2 o;
    o.x = packbf(v.x, v.y);
    o.y = packbf(v.z, v.w);
    *((uint2*)dst + i) = o;
  }
}

// ---------------- weights: f32 -> bf16 packed chunk-major ------------------
// dst idx (bf16 units) = kt64*(Opack*64) + chunk*(Opack*8) + (col+colOff)*8 + j
// holds src[col][kt64*64 + chunk*8 + j], chunk in 0..7.
struct PackJob { const float* src; unsigned short* dst; int O; int K; int colOff; int Opack; };
struct PackJobs { PackJob j[10]; };

__global__ __launch_bounds__(256)
void k_pack_w(PackJobs jobs) {
  const PackJob J = jobs.j[blockIdx.y];
  const int total = J.O * J.K / 2;  // u32 outputs, source-major
  for (int u = blockIdx.x * blockDim.x + threadIdx.x; u < total; u += gridDim.x * blockDim.x) {
    const int e = u * 2;
    const int col = e / J.K;
    const int k = e - col * J.K;
    const int kt = k >> 6, ch = (k >> 3) & 7, j = k & 7;
    const float f0 = J.src[(size_t)col * J.K + k];
    const float f1 = J.src[(size_t)col * J.K + k + 1];
    const int didx = kt * (J.Opack * 64) + ch * (J.Opack * 8) + (col + J.colOff) * 8 + j;
    ((unsigned int*)J.dst)[didx >> 1] = packbf(f0, f1);
  }
}

// ---------------- mean aggregation, bf16 in/out, f32 accum -----------------
static __device__ __forceinline__ void acc_u4(float* acc, const uint4& v) {
  acc[0] += lo16(v.x); acc[1] += hi16(v.x);
  acc[2] += lo16(v.y); acc[3] += hi16(v.y);
  acc[4] += lo16(v.z); acc[5] += hi16(v.z);
  acc[6] += lo16(v.w); acc[7] += hi16(v.w);
}

// K=128: row = 16 uint4; 4 subgroups of 16 lanes; 4 edges per load instr.
__global__ __launch_bounds__(256)
void k_agg128(const unsigned short* __restrict__ h, const int* __restrict__ row_off,
              const int* __restrict__ esrc, const float* __restrict__ deg_inv,
              unsigned short* __restrict__ agg, int N) {
  const int node = blockIdx.x * 4 + (threadIdx.x >> 6);
  if (node >= N) return;
  const int lane = threadIdx.x & 63;
  const int g = lane >> 4, c = lane & 15;
  const int s0 = row_off[node], s1 = row_off[node + 1];
  const uint4* hp = (const uint4*)h;
  float acc[8] = {0.f, 0.f, 0.f, 0.f, 0.f, 0.f, 0.f, 0.f};
  for (int i = s0; i < s1; i += 16) {
    int el = i + (lane & 15);
    if (el >= s1) el = s1 - 1;
    const int ev = esrc[el];
    uint4 v[4];
#pragma unroll
    for (int u = 0; u < 4; ++u) {
      if (i + u * 4 < s1) {
        const int e = __shfl(ev, u * 4 + g);
        v[u] = hp[(size_t)e * 16 + c];
      }
    }
#pragma unroll
    for (int u = 0; u < 4; ++u)
      if (i + u * 4 + g < s1) acc_u4(acc, v[u]);
  }
#pragma unroll
  for (int j = 0; j < 8; ++j) {
    acc[j] += __shfl_xor(acc[j], 16);
    acc[j] += __shfl_xor(acc[j], 32);
  }
  if (g == 0) {
    const float di = deg_inv[node];
    uint4 o;
    o.x = packbf(acc[0] * di, acc[1] * di);
    o.y = packbf(acc[2] * di, acc[3] * di);
    o.z = packbf(acc[4] * di, acc[5] * di);
    o.w = packbf(acc[6] * di, acc[7] * di);
    ((uint4*)agg)[(size_t)node * 16 + c] = o;
  }
}

// K=256: row = 32 uint4; 2 subgroups of 32 lanes; 2 edges per load instr.
__global__ __launch_bounds__(256)
void k_agg256(const unsigned short* __restrict__ h, const int* __restrict__ row_off,
              const int* __restrict__ esrc, const float* __restrict__ deg_inv,
              unsigned short* __restrict__ agg, int N) {
  const int node = blockIdx.x * 4 + (threadIdx.x >> 6);
  if (node >= N) return;
  const int lane = threadIdx.x & 63;
  const int g = lane >> 5, c = lane & 31;
  const int s0 = row_off[node], s1 = row_off[node + 1];
  const uint4* hp = (const uint4*)h;
  float acc[8] = {0.f, 0.f, 0.f, 0.f, 0.f, 0.f, 0.f, 0.f};
  for (int i = s0; i < s1; i += 16) {
    int el = i + (lane & 15);
    if (el >= s1) el = s1 - 1;
    const int ev = esrc[el];
    uint4 v[8];
#pragma unroll
    for (int u = 0; u < 8; ++u) {
      if (i + u * 2 < s1) {
        const int e = __shfl(ev, u * 2 + g);
        v[u] = hp[(size_t)e * 32 + c];
      }
    }
#pragma unroll
    for (int u = 0; u < 8; ++u)
      if (i + u * 2 + g < s1) acc_u4(acc, v[u]);
  }
#pragma unroll
  for (int j = 0; j < 8; ++j) acc[j] += __shfl_xor(acc[j], 32);
  if (g == 0) {
    const float di = deg_inv[node];
    uint4 o;
    o.x = packbf(acc[0] * di, acc[1] * di);
    o.y = packbf(acc[2] * di, acc[3] * di);
    o.z = packbf(acc[4] * di, acc[5] * di);
    o.w = packbf(acc[6] * di, acc[7] * di);
    ((uint4*)agg)[(size_t)node * 32 + c] = o;
  }
}

// K=64: row = 8 uint4; 8 subgroups of 8 lanes; 8 edges per load instr.
__global__ __launch_bounds__(256)
void k_agg64(const unsigned short* __restrict__ h, const int* __restrict__ row_off,
             const int* __restrict__ esrc, const float* __restrict__ deg_inv,
             unsigned short* __restrict__ agg, int N) {
  const int node = blockIdx.x * 4 + (threadIdx.x >> 6);
  if (node >= N) return;
  const int lane = threadIdx.x & 63;
  const int g = lane >> 3, c = lane & 7;
  const int s0 = row_off[node], s1 = row_off[node + 1];
  const uint4* hp = (const uint4*)h;
  float acc[8] = {0.f, 0.f, 0.f, 0.f, 0.f, 0.f, 0.f, 0.f};
  for (int i = s0; i < s1; i += 16) {
    int el = i + (lane & 15);
    if (el >= s1) el = s1 - 1;
    const int ev = esrc[el];
    uint4 v[2];
#pragma unroll
    for (int u = 0; u < 2; ++u) {
      if (i + u * 8 < s1) {
        const int e = __shfl(ev, u * 8 + g);
        v[u] = hp[(size_t)e * 8 + c];
      }
    }
#pragma unroll
    for (int u = 0; u < 2; ++u)
      if (i + u * 8 + g < s1) acc_u4(acc, v[u]);
  }
#pragma unroll
  for (int j = 0; j < 8; ++j) {
    acc[j] += __shfl_xor(acc[j], 8);
    acc[j] += __shfl_xor(acc[j], 16);
    acc[j] += __shfl_xor(acc[j], 32);
  }
  if (g == 0) {
    const float di = deg_inv[node];
    uint4 o;
    o.x = packbf(acc[0] * di, acc[1] * di);
    o.y = packbf(acc[2] * di, acc[3] * di);
    o.z = packbf(acc[4] * di, acc[5] * di);
    o.w = packbf(acc[6] * di, acc[7] * di);
    ((uint4*)agg)[(size_t)node * 8 + c] = o;
  }
}

// L1 fused post-transform aggregate: z = [Zl | Yr] (N x 128 bf16).
// out[n][0..63] = relu(deg_inv[n] * sum_e Zl[src(e)] + Yr[n] + bias).
__global__ __launch_bounds__(256)
void k_agg_post64(const unsigned short* __restrict__ z, const int* __restrict__ row_off,
                  const int* __restrict__ esrc, const float* __restrict__ deg_inv,
                  const float* __restrict__ bias, unsigned short* __restrict__ out, int N) {
  const int node = blockIdx.x * 4 + (threadIdx.x >> 6);
  if (node >= N) return;
  const int lane = threadIdx.x & 63;
  const int g = lane >> 3, c = lane & 7;
  const int s0 = row_off[node], s1 = row_off[node + 1];
  const uint4* zp = (const uint4*)z;   // row = 16 uint4; Zl = first 8
  float acc[8] = {0.f, 0.f, 0.f, 0.f, 0.f, 0.f, 0.f, 0.f};
  for (int i = s0; i < s1; i += 16) {
    int el = i + (lane & 15);
    if (el >= s1) el = s1 - 1;
    const int ev = esrc[el];
    uint4 v[2];
#pragma unroll
    for (int u = 0; u < 2; ++u) {
      if (i + u * 8 < s1) {
        const int e = __shfl(ev, u * 8 + g);
        v[u] = zp[(size_t)e * 16 + c];
      }
    }
#pragma unroll
    for (int u = 0; u < 2; ++u)
      if (i + u * 8 + g < s1) acc_u4(acc, v[u]);
  }
#pragma unroll
  for (int j = 0; j < 8; ++j) {
    acc[j] += __shfl_xor(acc[j], 8);
    acc[j] += __shfl_xor(acc[j], 16);
    acc[j] += __shfl_xor(acc[j], 32);
  }
  if (g == 0) {
    const float di = deg_inv[node];
    const uint4 yr = zp[(size_t)node * 16 + 8 + c];
    float y[8];
    y[0] = lo16(yr.x); y[1] = hi16(yr.x); y[2] = lo16(yr.y); y[3] = hi16(yr.y);
    y[4] = lo16(yr.z); y[5] = hi16(yr.z); y[6] = lo16(yr.w); y[7] = hi16(yr.w);
    float r[8];
#pragma unroll
    for (int j = 0; j < 8; ++j)
      r[j] = fmaxf(acc[j] * di + y[j] + bias[c * 8 + j], 0.f);
    uint4 o;
    o.x = packbf(r[0], r[1]);
    o.y = packbf(r[2], r[3]);
    o.z = packbf(r[4], r[5]);
    o.w = packbf(r[6], r[7]);
    ((uint4*)out)[(size_t)node * 8 + c] = o;
  }
}

// ---------------- fused SAGE GEMM ------------------------------------------
// FUSED=true : C = relu(A0@B0p^T + A1@B1p^T + bias)  (two phases)
// FUSED=false: C = A0@B0p^T                           (single phase, raw)
// Block: 128 rows x BN=WC*64 cols; 2 x WC waves; MFMA 32x32x16; BK=64.
// 1D grid, XCD-co-located decode: r8=bid&7, cb=(bid>>3)%NCB, rowp=((bid>>3)/NCB)*8+r8
// -> the NCB col-blocks of a row-panel share bid%8 (same XCD) => A reuse in L2.
template <int WC, int NCB, bool FUSED>
__global__ __launch_bounds__(WC * 128)
void k_sage_gemm(const unsigned short* __restrict__ A0, const unsigned short* __restrict__ B0,
                 const unsigned short* __restrict__ A1, const unsigned short* __restrict__ B1,
                 const float* __restrict__ bias, unsigned short* __restrict__ C,
                 int Nn, int K, int O) {
  constexpr int BN = WC * 64;
  constexpr int T = WC * 128;
  constexpr int ACH = 1024;            // A 16B-chunks per tile (128 rows x 8)
  constexpr int BCH = BN * 8;          // B 16B-chunks per tile
  constexpr int LPT = (ACH + BCH) / T; // chunks per thread per stage
  constexpr int BSH = (WC == 1) ? 6 : ((WC == 2) ? 7 : 8);  // log2(BN)
  constexpr int LDSBUF = 16384 + BN * 128;
  __shared__ char lds[2 * LDSBUF];

  const int nrp = (Nn + 127) >> 7;
  const int bid = blockIdx.x;
  const int r8 = bid & 7;
  const int tb = bid >> 3;
  const int cb = tb % NCB;
  const int rowp = (tb / NCB) * 8 + r8;
  if (rowp >= nrp) return;

  const int tid = threadIdx.x;
  const int w = tid >> 6, lane = tid & 63;
  const int wr = w / WC, wc = w % WC;
  const int fr = lane & 31, fq = lane >> 5;
  const int row0 = rowp * 128 + wr * 64;
  const int colb = cb * BN;

  const int KT0 = K >> 6;        // 64-wide tiles per phase
  const int NT = FUSED ? 2 * KT0 : KT0;

  f32x16 acc[2][2];
#pragma unroll
  for (int m = 0; m < 2; ++m)
#pragma unroll
    for (int cn = 0; cn < 2; ++cn)
#pragma unroll
      for (int r = 0; r < 16; ++r) acc[m][cn][r] = 0.f;

  auto stage = [&](int buf, int t) {
    const unsigned short* Ab;
    const unsigned short* Bb;
    int ktl;
    if (FUSED) {
      const int ph = (t >= KT0) ? 1 : 0;
      Ab = ph ? A1 : A0;
      Bb = ph ? B1 : B0;
      ktl = t - ph * KT0;
    } else {
      Ab = A0; Bb = B0; ktl = t;
    }
    char* lb = lds + buf * LDSBUF;
#pragma unroll
    for (int i = 0; i < LPT; ++i) {
      const int ch = tid + i * T;
      if (ch < ACH) {
        const int ar = ch >> 3, s = ch & 7;         // LDS row, slot
        int g = rowp * 128 + ar;
        if (g >= Nn) g = Nn - 1;
        // inverse-swizzled global source; linear LDS dest
        gl_lds16(Ab + (size_t)g * K + ktl * 64 + ((s ^ (ar & 7)) << 3), lb + ch * 16);
      } else {
        const int cbch = ch - ACH;
        const int chunk = cbch >> BSH, colrel = cbch & (BN - 1);
        gl_lds16(Bb + (size_t)ktl * O * 64 + chunk * O * 8 + (colb + colrel) * 8,
                 lb + 16384 + cbch * 16);
      }
    }
  };

  stage(0, 0);
#pragma unroll 1
  for (int t = 0; t < NT; ++t) {
    asm volatile("s_waitcnt vmcnt(0)" ::: "memory");
    __syncthreads();
    if (t + 1 < NT) stage((t + 1) & 1, t + 1);
    const char* lb = lds + (t & 1) * LDSBUF;
#pragma unroll
    for (int k16i = 0; k16i < 4; ++k16i) {
      const int c = k16i * 2 + fq;                  // chunk 0..7
      bf16x8 af[2], bg[2];
#pragma unroll
      for (int m = 0; m < 2; ++m) {
        const int rl = wr * 64 + m * 32 + fr;
        af[m] = *(const bf16x8*)(lb + rl * 128 + ((c ^ (rl & 7)) << 4));
      }
#pragma unroll
      for (int cn = 0; cn < 2; ++cn) {
        const int colrel = wc * 64 + cn * 32 + fr;
        bg[cn] = *(const bf16x8*)(lb + 16384 + c * (BN * 16) + colrel * 16);
      }
#pragma unroll
      for (int m = 0; m < 2; ++m)
#pragma unroll
        for (int cn = 0; cn < 2; ++cn)
          acc[m][cn] = __builtin_amdgcn_mfma_f32_32x32x16_bf16(af[m], bg[cn], acc[m][cn], 0, 0, 0);
    }
  }

  // epilogue. C/D map: col = lane&31, row = (reg&3) + 8*(reg>>2) + 4*(lane>>5).
#pragma unroll
  for (int cn = 0; cn < 2; ++cn) {
    const int col = colb + wc * 64 + cn * 32 + fr;
    float bb = 0.f;
    if (FUSED) bb = bias[col];
#pragma unroll
    for (int m = 0; m < 2; ++m) {
#pragma unroll
      for (int reg = 0; reg < 16; ++reg) {
        float v = acc[m][cn][reg];
        if (FUSED) v = fmaxf(v + bb, 0.f);
        const float nb = __shfl_xor(v, 1);
        const int row = row0 + m * 32 + (reg & 3) + 8 * (reg >> 2) + 4 * fq;
        if (!(lane & 1) && row < Nn) {
          *(unsigned int*)(C + (size_t)row * O + col) = packbf(v, nb);
        }
      }
    }
  }
}

// ---------------- head: logits(512->4) + softmax, 4 waves per block --------
__global__ __launch_bounds__(256)
void k_out_softmax(const unsigned short* __restrict__ h, const float* __restrict__ W4,
                   const float* __restrict__ b, float* __restrict__ out, int N) {
  const int n = blockIdx.x * 4 + (threadIdx.x >> 6);
  if (n >= N) return;
  const int lane = threadIdx.x & 63;
  const unsigned int* hp = (const unsigned int*)h + (size_t)n * 256;
  float a[4] = {0.f, 0.f, 0.f, 0.f};
#pragma unroll
  for (int it = 0; it < 4; ++it) {
    const unsigned int v = hp[it * 64 + lane];
    const float lo = lo16(v);
    const float hi = hi16(v);
    const int k = (it * 64 + lane) * 2;
#pragma unroll
    for (int c = 0; c < 4; ++c)
      a[c] += lo * W4[c * 512 + k] + hi * W4[c * 512 + k + 1];
  }
#pragma unroll
  for (int off = 32; off > 0; off >>= 1) {
#pragma unroll
    for (int c = 0; c < 4; ++c) a[c] += __shfl_down(a[c], off);
  }
  if (lane == 0) {
    const float l0 = a[0] + b[0], l1 = a[1] + b[1], l2 = a[2] + b[2], l3 = a[3] + b[3];
    const float m = fmaxf(fmaxf(l0, l1), fmaxf(l2, l3));
    const float e0 = expf(l0 - m), e1 = expf(l1 - m), e2 = expf(l2 - m), e3 = expf(l3 - m);
    const float inv = 1.0f / (e0 + e1 + e2 + e3);
    float4 r; r.x = e0 * inv; r.y = e1 * inv; r.z = e2 * inv; r.w = e3 * inv;
    *(float4*)(out + (size_t)n * 4) = r;
  }
}

// ---------------------------------------------------------------------------
extern "C" void kernel_launch(void* const* d_in, const int* in_sizes, int n_in,
                              void* d_out, int out_size, void* d_ws, size_t ws_size,
                              hipStream_t stream) {
  const float* x = (const float*)d_in[0];
  const float* Wl[5] = {(const float*)d_in[1], (const float*)d_in[4], (const float*)d_in[7],
                        (const float*)d_in[10], (const float*)d_in[13]};
  const float* bl[5] = {(const float*)d_in[2], (const float*)d_in[5], (const float*)d_in[8],
                        (const float*)d_in[11], (const float*)d_in[14]};
  const float* Wr[5] = {(const float*)d_in[3], (const float*)d_in[6], (const float*)d_in[9],
                        (const float*)d_in[12], (const float*)d_in[15]};
  const float* Wout = (const float*)d_in[16];
  const float* bout = (const float*)d_in[17];
  const int* eidx = (const int*)d_in[18];

  const int N = in_sizes[0] / 128;
  const int E = in_sizes[18] / 2;
  const int* srcI = eidx;
  const int* dstI = eidx + E;

  const int Kd[5] = {128, 128, 64, 128, 256};
  const int Od[5] = {128, 64, 128, 256, 512};

  // workspace carve-out (256B aligned)
  char* ws = (char*)d_ws;
  size_t p = 0;
  auto alloc = [&](size_t bytes) { size_t r = p; p += (bytes + 255) & ~(size_t)255; return r; };
  int*   deg     = (int*)(ws + alloc((size_t)N * 4));
  int*   row_off = (int*)(ws + alloc((size_t)(N + 1) * 4));
  int*   cursor  = (int*)(ws + alloc((size_t)N * 4));
  float* deg_inv = (float*)(ws + alloc((size_t)N * 4));
  int*   esrc    = (int*)(ws + alloc((size_t)E * 4));
  unsigned short* xb = (unsigned short*)(ws + alloc((size_t)N * 128 * 2));
  unsigned short* wlb[5];
  unsigned short* wrb[5];
  for (int l = 0; l < 5; ++l) {
    wlb[l] = (unsigned short*)(ws + alloc((size_t)Od[l] * Kd[l] * 2));
    wrb[l] = (unsigned short*)(ws + alloc((size_t)Od[l] * Kd[l] * 2));
  }
  unsigned short* wcat1 = (unsigned short*)(ws + alloc((size_t)128 * 128 * 2));
  unsigned short* bufA = (unsigned short*)(ws + alloc((size_t)N * 512 * 2));
  unsigned short* bufB = (unsigned short*)(ws + alloc((size_t)N * 256 * 2));
  unsigned short* agg  = (unsigned short*)(ws + alloc((size_t)N * 256 * 2));
  (void)ws_size; (void)n_in; (void)out_size;

  // ---- conversions: x plain; weights packed chunk-major ----
  k_conv_x<<<128, 256, 0, stream>>>(x, xb, N * 128 / 4);
  PackJobs jobs;
  for (int l = 0; l < 5; ++l) {
    if (l == 1) {
      jobs.j[2] = {Wl[1], wcat1, 64, 128, 0, 128};   // Zl cols 0..63
      jobs.j[3] = {Wr[1], wcat1, 64, 128, 64, 128};  // Yr cols 64..127
    } else {
      jobs.j[2 * l]     = {Wl[l], wlb[l], Od[l], Kd[l], 0, Od[l]};
      jobs.j[2 * l + 1] = {Wr[l], wrb[l], Od[l], Kd[l], 0, Od[l]};
    }
  }
  k_pack_w<<<dim3(32, 10), 256, 0, stream>>>(jobs);

  // ---- CSR build ----
  hipMemsetAsync(deg, 0, (size_t)N * 4, stream);
  k_count_deg<<<idiv_up(E, 256), 256, 0, stream>>>(dstI, deg, E);
  k_scan<<<1, 1024, 0, stream>>>(deg, row_off, cursor, deg_inv, N);
  k_fill_csr<<<idiv_up(E, 256), 256, 0, stream>>>(srcI, dstI, cursor, esrc, E);

  const int gx8 = 8 * ((idiv_up(N, 128) + 7) / 8);   // padded row-panel grid

  // ---- layer 0: K=128, O=128 ----
  k_agg128<<<idiv_up(N, 4), 256, 0, stream>>>(xb, row_off, esrc, deg_inv, agg, N);
  k_sage_gemm<2, 1, true><<<gx8, 256, 0, stream>>>(agg, wlb[0], xb, wrb[0], bl[0], bufA, N, 128, 128);

  // ---- layer 1 (linearity swap): Z|Yr = h1 @ [Wl;Wr]^T, then fused agg ----
  k_sage_gemm<2, 1, false><<<gx8, 256, 0, stream>>>(bufA, wcat1, bufA, wcat1, bl[1], agg, N, 128, 128);
  k_agg_post64<<<idiv_up(N, 4), 256, 0, stream>>>(agg, row_off, esrc, deg_inv, bl[1], bufB, N);

  // ---- layer 2: K=64, O=128 ----
  k_agg64<<<idiv_up(N, 4), 256, 0, stream>>>(bufB, row_off, esrc, deg_inv, agg, N);
  k_sage_gemm<2, 1, true><<<gx8, 256, 0, stream>>>(agg, wlb[2], bufB, wrb[2], bl[2], bufA, N, 64, 128);

  // ---- layer 3: K=128, O=256 (2 col-blocks, XCD-co-located) ----
  k_agg128<<<idiv_up(N, 4), 256, 0, stream>>>(bufA, row_off, esrc, deg_inv, agg, N);
  k_sage_gemm<2, 2, true><<<2 * gx8, 256, 0, stream>>>(agg, wlb[3], bufA, wrb[3], bl[3], bufB, N, 128, 256);

  // ---- layer 4: K=256, O=512 (4 col-blocks, XCD-co-located) ----
  k_agg256<<<idiv_up(N, 4), 256, 0, stream>>>(bufB, row_off, esrc, deg_inv, agg, N);
  k_sage_gemm<2, 4, true><<<4 * gx8, 256, 0, stream>>>(agg, wlb[4], bufB, wrb[4], bl[4], bufA, N, 256, 512);

  k_out_softmax<<<idiv_up(N, 4), 256, 0, stream>>>(bufA, Wout, bout, (float*)d_out, N);
}

// Round 12
// 414.851 us; speedup vs baseline: 1.4136x; 1.1134x over previous
//
#include <hip/hip_runtime.h>
#include <hip/hip_bf16.h>
#include <cstdint>
#include <cstddef>

// ---------------------------------------------------------------------------
// SAGE GNN forward, bf16 MFMA 32x32x16, LDS-staged GEMM, BK=64.
//  - GEMM: round-6 schedule + XCD-co-located col-blocks; NEW: B operands read
//    direct from global (packed, L2-resident) -> LDS 32KB -> 5 blocks/CU
//  - L1: linearity swap (raw GEMM then 64-wide fused aggregate)
//  - aggregates: uint4 lanes, 16-edge shfl-broadcast batches
//  - NEW: multi-block hierarchical CSR scan
// ---------------------------------------------------------------------------

typedef short bf16x8 __attribute__((ext_vector_type(8)));   // 8 bf16 = 4 VGPRs
typedef float f32x16 __attribute__((ext_vector_type(16)));

static inline int idiv_up(int a, int b) { return (a + b - 1) / b; }

static __device__ __forceinline__ float bf2f(unsigned short u) {
  union { unsigned int i; float f; } v; v.i = ((unsigned int)u) << 16; return v.f;
}
static __device__ __forceinline__ unsigned short f2bf(float f) {
  union { float f; unsigned int i; } v; v.f = f;
  return (unsigned short)((v.i + 0x7FFFu + ((v.i >> 16) & 1u)) >> 16);  // RNE
}
static __device__ __forceinline__ float lo16(unsigned int u) { return bf2f((unsigned short)(u & 0xffffu)); }
static __device__ __forceinline__ float hi16(unsigned int u) { return bf2f((unsigned short)(u >> 16)); }
static __device__ __forceinline__ unsigned int packbf(float a, float b) {
  return (unsigned int)f2bf(a) | ((unsigned int)f2bf(b) << 16);
}

// async global->LDS, 16B per lane. LDS dest: wave-uniform base + lane*16.
static __device__ __forceinline__ void gl_lds16(const void* g, void* l) {
  typedef __attribute__((address_space(3))) unsigned int lds_u32;
  typedef __attribute__((address_space(1))) const unsigned int glb_u32;
  __builtin_amdgcn_global_load_lds((glb_u32*)(uintptr_t)g,
                                   (lds_u32*)(unsigned int)(uintptr_t)l, 16, 0, 0);
}

// ---------------- CSR build ----------------
__global__ void k_count_deg(const int* __restrict__ dst, int* __restrict__ deg, int E) {
  int e = blockIdx.x * blockDim.x + threadIdx.x;
  if (e < E) atomicAdd(deg + dst[e], 1);
}

// pass 1: per-1024-block inclusive scan -> loc; block total -> part[bid]
__global__ __launch_bounds__(1024)
void k_scan1(const int* __restrict__ deg, int* __restrict__ loc, int* __restrict__ part, int n) {
  __shared__ int wsum[16];
  const int tid = threadIdx.x;
  const int lane = tid & 63, wid = tid >> 6;
  const int i = blockIdx.x * 1024 + tid;
  const int v = (i < n) ? deg[i] : 0;
  int incl = v;
#pragma unroll
  for (int off = 1; off < 64; off <<= 1) {
    int t = __shfl_up(incl, off);
    if (lane >= off) incl += t;
  }
  if (lane == 63) wsum[wid] = incl;
  __syncthreads();
  if (wid == 0) {
    int wv = (lane < 16) ? wsum[lane] : 0;
#pragma unroll
    for (int off = 1; off < 16; off <<= 1) {
      int t = __shfl_up(wv, off);
      if (lane >= off) wv += t;
    }
    if (lane < 16) wsum[lane] = wv;
  }
  __syncthreads();
  const int woff = (wid > 0) ? wsum[wid - 1] : 0;
  if (i < n) loc[i] = woff + incl;      // inclusive within block
  if (tid == 1023) part[blockIdx.x] = woff + incl;
}

// pass 2: single block scans nb (<=1024) partials -> exclusive; part[nb]=total
__global__ __launch_bounds__(1024)
void k_scan2(int* __restrict__ part, int nb) {
  __shared__ int wsum[16];
  const int tid = threadIdx.x;
  const int lane = tid & 63, wid = tid >> 6;
  const int v = (tid < nb) ? part[tid] : 0;
  int incl = v;
#pragma unroll
  for (int off = 1; off < 64; off <<= 1) {
    int t = __shfl_up(incl, off);
    if (lane >= off) incl += t;
  }
  if (lane == 63) wsum[wid] = incl;
  __syncthreads();
  if (wid == 0) {
    int wv = (lane < 16) ? wsum[lane] : 0;
#pragma unroll
    for (int off = 1; off < 16; off <<= 1) {
      int t = __shfl_up(wv, off);
      if (lane >= off) wv += t;
    }
    if (lane < 16) wsum[lane] = wv;
  }
  __syncthreads();
  const int woff = (wid > 0) ? wsum[wid - 1] : 0;
  if (tid < nb) part[tid] = woff + incl - v;  // exclusive
  if (tid == 0) part[nb] = wsum[15];          // total
}

// pass 3: apply offsets; emit row_off / cursor / deg_inv
__global__ __launch_bounds__(256)
void k_scan3(const int* __restrict__ deg, const int* __restrict__ loc, const int* __restrict__ part,
             int* __restrict__ row_off, int* __restrict__ cursor, float* __restrict__ deg_inv,
             int n, int nb) {
  const int i = blockIdx.x * blockDim.x + threadIdx.x;
  if (i < n) {
    const int v = deg[i];
    const int ro = part[i >> 10] + loc[i] - v;
    row_off[i] = ro;
    cursor[i] = ro;
    deg_inv[i] = 1.0f / (float)((v > 1) ? v : 1);
  }
  if (i == 0) row_off[n] = part[nb];
}

__global__ void k_fill_csr(const int* __restrict__ src, const int* __restrict__ dst,
                           int* __restrict__ cursor, int* __restrict__ esrc, int E) {
  int e = blockIdx.x * blockDim.x + threadIdx.x;
  if (e < E) {
    int d = dst[e];
    int p = atomicAdd(cursor + d, 1);
    esrc[p] = src[e];
  }
}

// ---------------- x: f32 -> bf16 plain conversion --------------------------
__global__ __launch_bounds__(256)
void k_conv_x(const float* __restrict__ src, unsigned short* __restrict__ dst, int n4) {
  for (int i = blockIdx.x * blockDim.x + threadIdx.x; i < n4; i += gridDim.x * blockDim.x) {
    const float4 v = *((const float4*)src + i);
    uint2 o;
    o.x = packbf(v.x, v.y);
    o.y = packbf(v.z, v.w);
    *((uint2*)dst + i) = o;
  }
}

// ---------------- weights: f32 -> bf16 packed chunk-major ------------------
// dst idx (bf16 units) = kt64*(Opack*64) + chunk*(Opack*8) + (col+colOff)*8 + j
// holds src[col][kt64*64 + chunk*8 + j], chunk in 0..7.
struct PackJob { const float* src; unsigned short* dst; int O; int K; int colOff; int Opack; };
struct PackJobs { PackJob j[10]; };

__global__ __launch_bounds__(256)
void k_pack_w(PackJobs jobs) {
  const PackJob J = jobs.j[blockIdx.y];
  const int total = J.O * J.K / 2;  // u32 outputs, source-major
  for (int u = blockIdx.x * blockDim.x + threadIdx.x; u < total; u += gridDim.x * blockDim.x) {
    const int e = u * 2;
    const int col = e / J.K;
    const int k = e - col * J.K;
    const int kt = k >> 6, ch = (k >> 3) & 7, j = k & 7;
    const float f0 = J.src[(size_t)col * J.K + k];
    const float f1 = J.src[(size_t)col * J.K + k + 1];
    const int didx = kt * (J.Opack * 64) + ch * (J.Opack * 8) + (col + J.colOff) * 8 + j;
    ((unsigned int*)J.dst)[didx >> 1] = packbf(f0, f1);
  }
}

// ---------------- mean aggregation, bf16 in/out, f32 accum -----------------
static __device__ __forceinline__ void acc_u4(float* acc, const uint4& v) {
  acc[0] += lo16(v.x); acc[1] += hi16(v.x);
  acc[2] += lo16(v.y); acc[3] += hi16(v.y);
  acc[4] += lo16(v.z); acc[5] += hi16(v.z);
  acc[6] += lo16(v.w); acc[7] += hi16(v.w);
}

// K=128: row = 16 uint4; 4 subgroups of 16 lanes; 4 edges per load instr.
__global__ __launch_bounds__(256)
void k_agg128(const unsigned short* __restrict__ h, const int* __restrict__ row_off,
              const int* __restrict__ esrc, const float* __restrict__ deg_inv,
              unsigned short* __restrict__ agg, int N) {
  const int node = blockIdx.x * 4 + (threadIdx.x >> 6);
  if (node >= N) return;
  const int lane = threadIdx.x & 63;
  const int g = lane >> 4, c = lane & 15;
  const int s0 = row_off[node], s1 = row_off[node + 1];
  const uint4* hp = (const uint4*)h;
  float acc[8] = {0.f, 0.f, 0.f, 0.f, 0.f, 0.f, 0.f, 0.f};
  for (int i = s0; i < s1; i += 16) {
    int el = i + (lane & 15);
    if (el >= s1) el = s1 - 1;
    const int ev = esrc[el];
    uint4 v[4];
#pragma unroll
    for (int u = 0; u < 4; ++u) {
      if (i + u * 4 < s1) {
        const int e = __shfl(ev, u * 4 + g);
        v[u] = hp[(size_t)e * 16 + c];
      }
    }
#pragma unroll
    for (int u = 0; u < 4; ++u)
      if (i + u * 4 + g < s1) acc_u4(acc, v[u]);
  }
#pragma unroll
  for (int j = 0; j < 8; ++j) {
    acc[j] += __shfl_xor(acc[j], 16);
    acc[j] += __shfl_xor(acc[j], 32);
  }
  if (g == 0) {
    const float di = deg_inv[node];
    uint4 o;
    o.x = packbf(acc[0] * di, acc[1] * di);
    o.y = packbf(acc[2] * di, acc[3] * di);
    o.z = packbf(acc[4] * di, acc[5] * di);
    o.w = packbf(acc[6] * di, acc[7] * di);
    ((uint4*)agg)[(size_t)node * 16 + c] = o;
  }
}

// K=256: row = 32 uint4; 2 subgroups of 32 lanes; 2 edges per load instr.
__global__ __launch_bounds__(256)
void k_agg256(const unsigned short* __restrict__ h, const int* __restrict__ row_off,
              const int* __restrict__ esrc, const float* __restrict__ deg_inv,
              unsigned short* __restrict__ agg, int N) {
  const int node = blockIdx.x * 4 + (threadIdx.x >> 6);
  if (node >= N) return;
  const int lane = threadIdx.x & 63;
  const int g = lane >> 5, c = lane & 31;
  const int s0 = row_off[node], s1 = row_off[node + 1];
  const uint4* hp = (const uint4*)h;
  float acc[8] = {0.f, 0.f, 0.f, 0.f, 0.f, 0.f, 0.f, 0.f};
  for (int i = s0; i < s1; i += 16) {
    int el = i + (lane & 15);
    if (el >= s1) el = s1 - 1;
    const int ev = esrc[el];
    uint4 v[8];
#pragma unroll
    for (int u = 0; u < 8; ++u) {
      if (i + u * 2 < s1) {
        const int e = __shfl(ev, u * 2 + g);
        v[u] = hp[(size_t)e * 32 + c];
      }
    }
#pragma unroll
    for (int u = 0; u < 8; ++u)
      if (i + u * 2 + g < s1) acc_u4(acc, v[u]);
  }
#pragma unroll
  for (int j = 0; j < 8; ++j) acc[j] += __shfl_xor(acc[j], 32);
  if (g == 0) {
    const float di = deg_inv[node];
    uint4 o;
    o.x = packbf(acc[0] * di, acc[1] * di);
    o.y = packbf(acc[2] * di, acc[3] * di);
    o.z = packbf(acc[4] * di, acc[5] * di);
    o.w = packbf(acc[6] * di, acc[7] * di);
    ((uint4*)agg)[(size_t)node * 32 + c] = o;
  }
}

// K=64: row = 8 uint4; 8 subgroups of 8 lanes; 8 edges per load instr.
__global__ __launch_bounds__(256)
void k_agg64(const unsigned short* __restrict__ h, const int* __restrict__ row_off,
             const int* __restrict__ esrc, const float* __restrict__ deg_inv,
             unsigned short* __restrict__ agg, int N) {
  const int node = blockIdx.x * 4 + (threadIdx.x >> 6);
  if (node >= N) return;
  const int lane = threadIdx.x & 63;
  const int g = lane >> 3, c = lane & 7;
  const int s0 = row_off[node], s1 = row_off[node + 1];
  const uint4* hp = (const uint4*)h;
  float acc[8] = {0.f, 0.f, 0.f, 0.f, 0.f, 0.f, 0.f, 0.f};
  for (int i = s0; i < s1; i += 16) {
    int el = i + (lane & 15);
    if (el >= s1) el = s1 - 1;
    const int ev = esrc[el];
    uint4 v[2];
#pragma unroll
    for (int u = 0; u < 2; ++u) {
      if (i + u * 8 < s1) {
        const int e = __shfl(ev, u * 8 + g);
        v[u] = hp[(size_t)e * 8 + c];
      }
    }
#pragma unroll
    for (int u = 0; u < 2; ++u)
      if (i + u * 8 + g < s1) acc_u4(acc, v[u]);
  }
#pragma unroll
  for (int j = 0; j < 8; ++j) {
    acc[j] += __shfl_xor(acc[j], 8);
    acc[j] += __shfl_xor(acc[j], 16);
    acc[j] += __shfl_xor(acc[j], 32);
  }
  if (g == 0) {
    const float di = deg_inv[node];
    uint4 o;
    o.x = packbf(acc[0] * di, acc[1] * di);
    o.y = packbf(acc[2] * di, acc[3] * di);
    o.z = packbf(acc[4] * di, acc[5] * di);
    o.w = packbf(acc[6] * di, acc[7] * di);
    ((uint4*)agg)[(size_t)node * 8 + c] = o;
  }
}

// L1 fused post-transform aggregate: z = [Zl | Yr] (N x 128 bf16).
// out[n][0..63] = relu(deg_inv[n] * sum_e Zl[src(e)] + Yr[n] + bias).
__global__ __launch_bounds__(256)
void k_agg_post64(const unsigned short* __restrict__ z, const int* __restrict__ row_off,
                  const int* __restrict__ esrc, const float* __restrict__ deg_inv,
                  const float* __restrict__ bias, unsigned short* __restrict__ out, int N) {
  const int node = blockIdx.x * 4 + (threadIdx.x >> 6);
  if (node >= N) return;
  const int lane = threadIdx.x & 63;
  const int g = lane >> 3, c = lane & 7;
  const int s0 = row_off[node], s1 = row_off[node + 1];
  const uint4* zp = (const uint4*)z;   // row = 16 uint4; Zl = first 8
  float acc[8] = {0.f, 0.f, 0.f, 0.f, 0.f, 0.f, 0.f, 0.f};
  for (int i = s0; i < s1; i += 16) {
    int el = i + (lane & 15);
    if (el >= s1) el = s1 - 1;
    const int ev = esrc[el];
    uint4 v[2];
#pragma unroll
    for (int u = 0; u < 2; ++u) {
      if (i + u * 8 < s1) {
        const int e = __shfl(ev, u * 8 + g);
        v[u] = zp[(size_t)e * 16 + c];
      }
    }
#pragma unroll
    for (int u = 0; u < 2; ++u)
      if (i + u * 8 + g < s1) acc_u4(acc, v[u]);
  }
#pragma unroll
  for (int j = 0; j < 8; ++j) {
    acc[j] += __shfl_xor(acc[j], 8);
    acc[j] += __shfl_xor(acc[j], 16);
    acc[j] += __shfl_xor(acc[j], 32);
  }
  if (g == 0) {
    const float di = deg_inv[node];
    const uint4 yr = zp[(size_t)node * 16 + 8 + c];
    float y[8];
    y[0] = lo16(yr.x); y[1] = hi16(yr.x); y[2] = lo16(yr.y); y[3] = hi16(yr.y);
    y[4] = lo16(yr.z); y[5] = hi16(yr.z); y[6] = lo16(yr.w); y[7] = hi16(yr.w);
    float r[8];
#pragma unroll
    for (int j = 0; j < 8; ++j)
      r[j] = fmaxf(acc[j] * di + y[j] + bias[c * 8 + j], 0.f);
    uint4 o;
    o.x = packbf(r[0], r[1]);
    o.y = packbf(r[2], r[3]);
    o.z = packbf(r[4], r[5]);
    o.w = packbf(r[6], r[7]);
    ((uint4*)out)[(size_t)node * 8 + c] = o;
  }
}

// ---------------- fused SAGE GEMM ------------------------------------------
// FUSED=true : C = relu(A0@B0p^T + A1@B1p^T + bias)  (two phases)
// FUSED=false: C = A0@B0p^T                           (single phase, raw)
// Block: 128 rows x BN=WC*64 cols; 2 x WC waves; MFMA 32x32x16; BK=64.
// A staged in LDS (32KB double-buffer -> 5 blocks/CU); B read DIRECT from
// global packed layout (coalesced 16B/lane, L2-resident).
// 1D grid, XCD-co-located decode: r8=bid&7, cb=(bid>>3)%NCB, rowp=((bid>>3)/NCB)*8+r8
template <int WC, int NCB, bool FUSED>
__global__ __launch_bounds__(WC * 128)
void k_sage_gemm(const unsigned short* __restrict__ A0, const unsigned short* __restrict__ B0,
                 const unsigned short* __restrict__ A1, const unsigned short* __restrict__ B1,
                 const float* __restrict__ bias, unsigned short* __restrict__ C,
                 int Nn, int K, int O) {
  constexpr int BN = WC * 64;
  constexpr int T = WC * 128;
  constexpr int ACH = 1024;            // A 16B-chunks per tile (128 rows x 8)
  constexpr int LPT = ACH / T;         // A chunks per thread per stage
  __shared__ char lds[2 * 16384];

  const int nrp = (Nn + 127) >> 7;
  const int bid = blockIdx.x;
  const int r8 = bid & 7;
  const int tb = bid >> 3;
  const int cb = tb % NCB;
  const int rowp = (tb / NCB) * 8 + r8;
  if (rowp >= nrp) return;

  const int tid = threadIdx.x;
  const int w = tid >> 6, lane = tid & 63;
  const int wr = w / WC, wc = w % WC;
  const int fr = lane & 31, fq = lane >> 5;
  const int row0 = rowp * 128 + wr * 64;
  const int colb = cb * BN;

  const int KT0 = K >> 6;        // 64-wide tiles per phase
  const int NT = FUSED ? 2 * KT0 : KT0;

  f32x16 acc[2][2];
#pragma unroll
  for (int m = 0; m < 2; ++m)
#pragma unroll
    for (int cn = 0; cn < 2; ++cn)
#pragma unroll
      for (int r = 0; r < 16; ++r) acc[m][cn][r] = 0.f;

  auto stage = [&](int buf, int t) {
    const unsigned short* Ab;
    int ktl;
    if (FUSED) {
      const int ph = (t >= KT0) ? 1 : 0;
      Ab = ph ? A1 : A0;
      ktl = t - ph * KT0;
    } else {
      Ab = A0; ktl = t;
    }
    char* lb = lds + buf * 16384;
#pragma unroll
    for (int i = 0; i < LPT; ++i) {
      const int ch = tid + i * T;
      const int ar = ch >> 3, s = ch & 7;           // LDS row, slot
      int g = rowp * 128 + ar;
      if (g >= Nn) g = Nn - 1;
      // inverse-swizzled global source; linear LDS dest
      gl_lds16(Ab + (size_t)g * K + ktl * 64 + ((s ^ (ar & 7)) << 3), lb + ch * 16);
    }
  };

  stage(0, 0);
#pragma unroll 1
  for (int t = 0; t < NT; ++t) {
    asm volatile("s_waitcnt vmcnt(0)" ::: "memory");
    __syncthreads();
    if (t + 1 < NT) stage((t + 1) & 1, t + 1);
    const char* lb = lds + (t & 1) * 16384;
    // B pointer for this tile (global, packed chunk-major)
    const unsigned short* Bp;
    int ktl;
    if (FUSED) {
      const int ph = (t >= KT0) ? 1 : 0;
      Bp = ph ? B1 : B0;
      ktl = t - ph * KT0;
    } else {
      Bp = B0; ktl = t;
    }
    const unsigned short* Bbase = Bp + (size_t)ktl * (O * 64) + (size_t)(colb + wc * 64) * 8;
#pragma unroll
    for (int k16i = 0; k16i < 4; ++k16i) {
      const int c = k16i * 2 + fq;                  // chunk 0..7
      bf16x8 af[2], bg[2];
#pragma unroll
      for (int m = 0; m < 2; ++m) {
        const int rl = wr * 64 + m * 32 + fr;
        af[m] = *(const bf16x8*)(lb + rl * 128 + ((c ^ (rl & 7)) << 4));
      }
#pragma unroll
      for (int cn = 0; cn < 2; ++cn)
        bg[cn] = *(const bf16x8*)(Bbase + (size_t)c * (O * 8) + (cn * 32 + fr) * 8);
#pragma unroll
      for (int m = 0; m < 2; ++m)
#pragma unroll
        for (int cn = 0; cn < 2; ++cn)
          acc[m][cn] = __builtin_amdgcn_mfma_f32_32x32x16_bf16(af[m], bg[cn], acc[m][cn], 0, 0, 0);
    }
  }

  // epilogue. C/D map: col = lane&31, row = (reg&3) + 8*(reg>>2) + 4*(lane>>5).
#pragma unroll
  for (int cn = 0; cn < 2; ++cn) {
    const int col = colb + wc * 64 + cn * 32 + fr;
    float bb = 0.f;
    if (FUSED) bb = bias[col];
#pragma unroll
    for (int m = 0; m < 2; ++m) {
#pragma unroll
      for (int reg = 0; reg < 16; ++reg) {
        float v = acc[m][cn][reg];
        if (FUSED) v = fmaxf(v + bb, 0.f);
        const float nb = __shfl_xor(v, 1);
        const int row = row0 + m * 32 + (reg & 3) + 8 * (reg >> 2) + 4 * fq;
        if (!(lane & 1) && row < Nn) {
          *(unsigned int*)(C + (size_t)row * O + col) = packbf(v, nb);
        }
      }
    }
  }
}

// ---------------- head: logits(512->4) + softmax, 4 waves per block --------
__global__ __launch_bounds__(256)
void k_out_softmax(const unsigned short* __restrict__ h, const float* __restrict__ W4,
                   const float* __restrict__ b, float* __restrict__ out, int N) {
  const int n = blockIdx.x * 4 + (threadIdx.x >> 6);
  if (n >= N) return;
  const int lane = threadIdx.x & 63;
  const unsigned int* hp = (const unsigned int*)h + (size_t)n * 256;
  float a[4] = {0.f, 0.f, 0.f, 0.f};
#pragma unroll
  for (int it = 0; it < 4; ++it) {
    const unsigned int v = hp[it * 64 + lane];
    const float lo = lo16(v);
    const float hi = hi16(v);
    const int k = (it * 64 + lane) * 2;
#pragma unroll
    for (int c = 0; c < 4; ++c)
      a[c] += lo * W4[c * 512 + k] + hi * W4[c * 512 + k + 1];
  }
#pragma unroll
  for (int off = 32; off > 0; off >>= 1) {
#pragma unroll
    for (int c = 0; c < 4; ++c) a[c] += __shfl_down(a[c], off);
  }
  if (lane == 0) {
    const float l0 = a[0] + b[0], l1 = a[1] + b[1], l2 = a[2] + b[2], l3 = a[3] + b[3];
    const float m = fmaxf(fmaxf(l0, l1), fmaxf(l2, l3));
    const float e0 = expf(l0 - m), e1 = expf(l1 - m), e2 = expf(l2 - m), e3 = expf(l3 - m);
    const float inv = 1.0f / (e0 + e1 + e2 + e3);
    float4 r; r.x = e0 * inv; r.y = e1 * inv; r.z = e2 * inv; r.w = e3 * inv;
    *(float4*)(out + (size_t)n * 4) = r;
  }
}

// ---------------------------------------------------------------------------
extern "C" void kernel_launch(void* const* d_in, const int* in_sizes, int n_in,
                              void* d_out, int out_size, void* d_ws, size_t ws_size,
                              hipStream_t stream) {
  const float* x = (const float*)d_in[0];
  const float* Wl[5] = {(const float*)d_in[1], (const float*)d_in[4], (const float*)d_in[7],
                        (const float*)d_in[10], (const float*)d_in[13]};
  const float* bl[5] = {(const float*)d_in[2], (const float*)d_in[5], (const float*)d_in[8],
                        (const float*)d_in[11], (const float*)d_in[14]};
  const float* Wr[5] = {(const float*)d_in[3], (const float*)d_in[6], (const float*)d_in[9],
                        (const float*)d_in[12], (const float*)d_in[15]};
  const float* Wout = (const float*)d_in[16];
  const float* bout = (const float*)d_in[17];
  const int* eidx = (const int*)d_in[18];

  const int N = in_sizes[0] / 128;
  const int E = in_sizes[18] / 2;
  const int* srcI = eidx;
  const int* dstI = eidx + E;

  const int Kd[5] = {128, 128, 64, 128, 256};
  const int Od[5] = {128, 64, 128, 256, 512};

  // workspace carve-out (256B aligned)
  char* ws = (char*)d_ws;
  size_t p = 0;
  auto alloc = [&](size_t bytes) { size_t r = p; p += (bytes + 255) & ~(size_t)255; return r; };
  int*   deg     = (int*)(ws + alloc((size_t)N * 4));
  int*   row_off = (int*)(ws + alloc((size_t)(N + 1) * 4));
  int*   cursor  = (int*)(ws + alloc((size_t)N * 4));
  float* deg_inv = (float*)(ws + alloc((size_t)N * 4));
  int*   loc     = (int*)(ws + alloc((size_t)N * 4));
  int*   part    = (int*)(ws + alloc((size_t)1032 * 4));
  int*   esrc    = (int*)(ws + alloc((size_t)E * 4));
  unsigned short* xb = (unsigned short*)(ws + alloc((size_t)N * 128 * 2));
  unsigned short* wlb[5];
  unsigned short* wrb[5];
  for (int l = 0; l < 5; ++l) {
    wlb[l] = (unsigned short*)(ws + alloc((size_t)Od[l] * Kd[l] * 2));
    wrb[l] = (unsigned short*)(ws + alloc((size_t)Od[l] * Kd[l] * 2));
  }
  unsigned short* wcat1 = (unsigned short*)(ws + alloc((size_t)128 * 128 * 2));
  unsigned short* bufA = (unsigned short*)(ws + alloc((size_t)N * 512 * 2));
  unsigned short* bufB = (unsigned short*)(ws + alloc((size_t)N * 256 * 2));
  unsigned short* agg  = (unsigned short*)(ws + alloc((size_t)N * 256 * 2));
  (void)ws_size; (void)n_in; (void)out_size;

  // ---- conversions: x plain; weights packed chunk-major ----
  k_conv_x<<<128, 256, 0, stream>>>(x, xb, N * 128 / 4);
  PackJobs jobs;
  for (int l = 0; l < 5; ++l) {
    if (l == 1) {
      jobs.j[2] = {Wl[1], wcat1, 64, 128, 0, 128};   // Zl cols 0..63
      jobs.j[3] = {Wr[1], wcat1, 64, 128, 64, 128};  // Yr cols 64..127
    } else {
      jobs.j[2 * l]     = {Wl[l], wlb[l], Od[l], Kd[l], 0, Od[l]};
      jobs.j[2 * l + 1] = {Wr[l], wrb[l], Od[l], Kd[l], 0, Od[l]};
    }
  }
  k_pack_w<<<dim3(32, 10), 256, 0, stream>>>(jobs);

  // ---- CSR build (multi-block scan) ----
  hipMemsetAsync(deg, 0, (size_t)N * 4, stream);
  k_count_deg<<<idiv_up(E, 256), 256, 0, stream>>>(dstI, deg, E);
  const int nb = idiv_up(N, 1024);
  k_scan1<<<nb, 1024, 0, stream>>>(deg, loc, part, N);
  k_scan2<<<1, 1024, 0, stream>>>(part, nb);
  k_scan3<<<idiv_up(N + 1, 256), 256, 0, stream>>>(deg, loc, part, row_off, cursor, deg_inv, N, nb);
  k_fill_csr<<<idiv_up(E, 256), 256, 0, stream>>>(srcI, dstI, cursor, esrc, E);

  const int gx8 = 8 * ((idiv_up(N, 128) + 7) / 8);   // padded row-panel grid

  // ---- layer 0: K=128, O=128 ----
  k_agg128<<<idiv_up(N, 4), 256, 0, stream>>>(xb, row_off, esrc, deg_inv, agg, N);
  k_sage_gemm<2, 1, true><<<gx8, 256, 0, stream>>>(agg, wlb[0], xb, wrb[0], bl[0], bufA, N, 128, 128);

  // ---- layer 1 (linearity swap): Z|Yr = h1 @ [Wl;Wr]^T, then fused agg ----
  k_sage_gemm<2, 1, false><<<gx8, 256, 0, stream>>>(bufA, wcat1, bufA, wcat1, bl[1], agg, N, 128, 128);
  k_agg_post64<<<idiv_up(N, 4), 256, 0, stream>>>(agg, row_off, esrc, deg_inv, bl[1], bufB, N);

  // ---- layer 2: K=64, O=128 ----
  k_agg64<<<idiv_up(N, 4), 256, 0, stream>>>(bufB, row_off, esrc, deg_inv, agg, N);
  k_sage_gemm<2, 1, true><<<gx8, 256, 0, stream>>>(agg, wlb[2], bufB, wrb[2], bl[2], bufA, N, 64, 128);

  // ---- layer 3: K=128, O=256 (2 col-blocks, XCD-co-located) ----
  k_agg128<<<idiv_up(N, 4), 256, 0, stream>>>(bufA, row_off, esrc, deg_inv, agg, N);
  k_sage_gemm<2, 2, true><<<2 * gx8, 256, 0, stream>>>(agg, wlb[3], bufA, wrb[3], bl[3], bufB, N, 128, 256);

  // ---- layer 4: K=256, O=512 (4 col-blocks, XCD-co-located) ----
  k_agg256<<<idiv_up(N, 4), 256, 0, stream>>>(bufB, row_off, esrc, deg_inv, agg, N);
  k_sage_gemm<2, 4, true><<<4 * gx8, 256, 0, stream>>>(agg, wlb[4], bufB, wrb[4], bl[4], bufA, N, 256, 512);

  k_out_softmax<<<idiv_up(N, 4), 256, 0, stream>>>(bufA, Wout, bout, (float*)d_out, N);
}

// Round 13
// 402.576 us; speedup vs baseline: 1.4567x; 1.0305x over previous
//
#include <hip/hip_runtime.h>
#include <hip/hip_bf16.h>
#include <cstdint>
#include <cstddef>

// ---------------------------------------------------------------------------
// SAGE GNN forward, bf16 MFMA 32x32x16, LDS-staged GEMM, BK=64.
//  - GEMM: round-6 schedule + XCD-co-located col-blocks; B direct from global
//    (packed, L2-resident); NEW: per-tile B loads hoisted before MFMA loop
//  - L1: linearity swap (raw GEMM then 64-wide fused aggregate)
//  - aggregates: uint4 lanes, 16-edge shfl-broadcast batches
//  - head: W4 staged in LDS
// ---------------------------------------------------------------------------

typedef short bf16x8 __attribute__((ext_vector_type(8)));   // 8 bf16 = 4 VGPRs
typedef float f32x16 __attribute__((ext_vector_type(16)));

static inline int idiv_up(int a, int b) { return (a + b - 1) / b; }

static __device__ __forceinline__ float bf2f(unsigned short u) {
  union { unsigned int i; float f; } v; v.i = ((unsigned int)u) << 16; return v.f;
}
static __device__ __forceinline__ unsigned short f2bf(float f) {
  union { float f; unsigned int i; } v; v.f = f;
  return (unsigned short)((v.i + 0x7FFFu + ((v.i >> 16) & 1u)) >> 16);  // RNE
}
static __device__ __forceinline__ float lo16(unsigned int u) { return bf2f((unsigned short)(u & 0xffffu)); }
static __device__ __forceinline__ float hi16(unsigned int u) { return bf2f((unsigned short)(u >> 16)); }
static __device__ __forceinline__ unsigned int packbf(float a, float b) {
  return (unsigned int)f2bf(a) | ((unsigned int)f2bf(b) << 16);
}

// async global->LDS, 16B per lane. LDS dest: wave-uniform base + lane*16.
static __device__ __forceinline__ void gl_lds16(const void* g, void* l) {
  typedef __attribute__((address_space(3))) unsigned int lds_u32;
  typedef __attribute__((address_space(1))) const unsigned int glb_u32;
  __builtin_amdgcn_global_load_lds((glb_u32*)(uintptr_t)g,
                                   (lds_u32*)(unsigned int)(uintptr_t)l, 16, 0, 0);
}

// ---------------- CSR build ----------------
__global__ void k_count_deg(const int* __restrict__ dst, int* __restrict__ deg, int E) {
  int e = blockIdx.x * blockDim.x + threadIdx.x;
  if (e < E) atomicAdd(deg + dst[e], 1);
}

// pass 1: per-1024-block inclusive scan -> loc; block total -> part[bid]
__global__ __launch_bounds__(1024)
void k_scan1(const int* __restrict__ deg, int* __restrict__ loc, int* __restrict__ part, int n) {
  __shared__ int wsum[16];
  const int tid = threadIdx.x;
  const int lane = tid & 63, wid = tid >> 6;
  const int i = blockIdx.x * 1024 + tid;
  const int v = (i < n) ? deg[i] : 0;
  int incl = v;
#pragma unroll
  for (int off = 1; off < 64; off <<= 1) {
    int t = __shfl_up(incl, off);
    if (lane >= off) incl += t;
  }
  if (lane == 63) wsum[wid] = incl;
  __syncthreads();
  if (wid == 0) {
    int wv = (lane < 16) ? wsum[lane] : 0;
#pragma unroll
    for (int off = 1; off < 16; off <<= 1) {
      int t = __shfl_up(wv, off);
      if (lane >= off) wv += t;
    }
    if (lane < 16) wsum[lane] = wv;
  }
  __syncthreads();
  const int woff = (wid > 0) ? wsum[wid - 1] : 0;
  if (i < n) loc[i] = woff + incl;      // inclusive within block
  if (tid == 1023) part[blockIdx.x] = woff + incl;
}

// pass 2: single block scans nb (<=1024) partials -> exclusive; part[nb]=total
__global__ __launch_bounds__(1024)
void k_scan2(int* __restrict__ part, int nb) {
  __shared__ int wsum[16];
  const int tid = threadIdx.x;
  const int lane = tid & 63, wid = tid >> 6;
  const int v = (tid < nb) ? part[tid] : 0;
  int incl = v;
#pragma unroll
  for (int off = 1; off < 64; off <<= 1) {
    int t = __shfl_up(incl, off);
    if (lane >= off) incl += t;
  }
  if (lane == 63) wsum[wid] = incl;
  __syncthreads();
  if (wid == 0) {
    int wv = (lane < 16) ? wsum[lane] : 0;
#pragma unroll
    for (int off = 1; off < 16; off <<= 1) {
      int t = __shfl_up(wv, off);
      if (lane >= off) wv += t;
    }
    if (lane < 16) wsum[lane] = wv;
  }
  __syncthreads();
  const int woff = (wid > 0) ? wsum[wid - 1] : 0;
  if (tid < nb) part[tid] = woff + incl - v;  // exclusive
  if (tid == 0) part[nb] = wsum[15];          // total
}

// pass 3: apply offsets; emit row_off / cursor / deg_inv
__global__ __launch_bounds__(256)
void k_scan3(const int* __restrict__ deg, const int* __restrict__ loc, const int* __restrict__ part,
             int* __restrict__ row_off, int* __restrict__ cursor, float* __restrict__ deg_inv,
             int n, int nb) {
  const int i = blockIdx.x * blockDim.x + threadIdx.x;
  if (i < n) {
    const int v = deg[i];
    const int ro = part[i >> 10] + loc[i] - v;
    row_off[i] = ro;
    cursor[i] = ro;
    deg_inv[i] = 1.0f / (float)((v > 1) ? v : 1);
  }
  if (i == 0) row_off[n] = part[nb];
}

__global__ void k_fill_csr(const int* __restrict__ src, const int* __restrict__ dst,
                           int* __restrict__ cursor, int* __restrict__ esrc, int E) {
  int e = blockIdx.x * blockDim.x + threadIdx.x;
  if (e < E) {
    int d = dst[e];
    int p = atomicAdd(cursor + d, 1);
    esrc[p] = src[e];
  }
}

// ---------------- x: f32 -> bf16 plain conversion --------------------------
__global__ __launch_bounds__(256)
void k_conv_x(const float* __restrict__ src, unsigned short* __restrict__ dst, int n4) {
  for (int i = blockIdx.x * blockDim.x + threadIdx.x; i < n4; i += gridDim.x * blockDim.x) {
    const float4 v = *((const float4*)src + i);
    uint2 o;
    o.x = packbf(v.x, v.y);
    o.y = packbf(v.z, v.w);
    *((uint2*)dst + i) = o;
  }
}

// ---------------- weights: f32 -> bf16 packed chunk-major ------------------
// dst idx (bf16 units) = kt64*(Opack*64) + chunk*(Opack*8) + (col+colOff)*8 + j
// holds src[col][kt64*64 + chunk*8 + j], chunk in 0..7.
struct PackJob { const float* src; unsigned short* dst; int O; int K; int colOff; int Opack; };
struct PackJobs { PackJob j[10]; };

__global__ __launch_bounds__(256)
void k_pack_w(PackJobs jobs) {
  const PackJob J = jobs.j[blockIdx.y];
  const int total = J.O * J.K / 2;  // u32 outputs, source-major
  for (int u = blockIdx.x * blockDim.x + threadIdx.x; u < total; u += gridDim.x * blockDim.x) {
    const int e = u * 2;
    const int col = e / J.K;
    const int k = e - col * J.K;
    const int kt = k >> 6, ch = (k >> 3) & 7, j = k & 7;
    const float f0 = J.src[(size_t)col * J.K + k];
    const float f1 = J.src[(size_t)col * J.K + k + 1];
    const int didx = kt * (J.Opack * 64) + ch * (J.Opack * 8) + (col + J.colOff) * 8 + j;
    ((unsigned int*)J.dst)[didx >> 1] = packbf(f0, f1);
  }
}

// ---------------- mean aggregation, bf16 in/out, f32 accum -----------------
static __device__ __forceinline__ void acc_u4(float* acc, const uint4& v) {
  acc[0] += lo16(v.x); acc[1] += hi16(v.x);
  acc[2] += lo16(v.y); acc[3] += hi16(v.y);
  acc[4] += lo16(v.z); acc[5] += hi16(v.z);
  acc[6] += lo16(v.w); acc[7] += hi16(v.w);
}

// K=128: row = 16 uint4; 4 subgroups of 16 lanes; 4 edges per load instr.
__global__ __launch_bounds__(256)
void k_agg128(const unsigned short* __restrict__ h, const int* __restrict__ row_off,
              const int* __restrict__ esrc, const float* __restrict__ deg_inv,
              unsigned short* __restrict__ agg, int N) {
  const int node = blockIdx.x * 4 + (threadIdx.x >> 6);
  if (node >= N) return;
  const int lane = threadIdx.x & 63;
  const int g = lane >> 4, c = lane & 15;
  const int s0 = row_off[node], s1 = row_off[node + 1];
  const uint4* hp = (const uint4*)h;
  float acc[8] = {0.f, 0.f, 0.f, 0.f, 0.f, 0.f, 0.f, 0.f};
  for (int i = s0; i < s1; i += 16) {
    int el = i + (lane & 15);
    if (el >= s1) el = s1 - 1;
    const int ev = esrc[el];
    uint4 v[4];
#pragma unroll
    for (int u = 0; u < 4; ++u) {
      if (i + u * 4 < s1) {
        const int e = __shfl(ev, u * 4 + g);
        v[u] = hp[(size_t)e * 16 + c];
      }
    }
#pragma unroll
    for (int u = 0; u < 4; ++u)
      if (i + u * 4 + g < s1) acc_u4(acc, v[u]);
  }
#pragma unroll
  for (int j = 0; j < 8; ++j) {
    acc[j] += __shfl_xor(acc[j], 16);
    acc[j] += __shfl_xor(acc[j], 32);
  }
  if (g == 0) {
    const float di = deg_inv[node];
    uint4 o;
    o.x = packbf(acc[0] * di, acc[1] * di);
    o.y = packbf(acc[2] * di, acc[3] * di);
    o.z = packbf(acc[4] * di, acc[5] * di);
    o.w = packbf(acc[6] * di, acc[7] * di);
    ((uint4*)agg)[(size_t)node * 16 + c] = o;
  }
}

// K=256: row = 32 uint4; 2 subgroups of 32 lanes; 2 edges per load instr.
__global__ __launch_bounds__(256)
void k_agg256(const unsigned short* __restrict__ h, const int* __restrict__ row_off,
              const int* __restrict__ esrc, const float* __restrict__ deg_inv,
              unsigned short* __restrict__ agg, int N) {
  const int node = blockIdx.x * 4 + (threadIdx.x >> 6);
  if (node >= N) return;
  const int lane = threadIdx.x & 63;
  const int g = lane >> 5, c = lane & 31;
  const int s0 = row_off[node], s1 = row_off[node + 1];
  const uint4* hp = (const uint4*)h;
  float acc[8] = {0.f, 0.f, 0.f, 0.f, 0.f, 0.f, 0.f, 0.f};
  for (int i = s0; i < s1; i += 16) {
    int el = i + (lane & 15);
    if (el >= s1) el = s1 - 1;
    const int ev = esrc[el];
    uint4 v[8];
#pragma unroll
    for (int u = 0; u < 8; ++u) {
      if (i + u * 2 < s1) {
        const int e = __shfl(ev, u * 2 + g);
        v[u] = hp[(size_t)e * 32 + c];
      }
    }
#pragma unroll
    for (int u = 0; u < 8; ++u)
      if (i + u * 2 + g < s1) acc_u4(acc, v[u]);
  }
#pragma unroll
  for (int j = 0; j < 8; ++j) acc[j] += __shfl_xor(acc[j], 32);
  if (g == 0) {
    const float di = deg_inv[node];
    uint4 o;
    o.x = packbf(acc[0] * di, acc[1] * di);
    o.y = packbf(acc[2] * di, acc[3] * di);
    o.z = packbf(acc[4] * di, acc[5] * di);
    o.w = packbf(acc[6] * di, acc[7] * di);
    ((uint4*)agg)[(size_t)node * 32 + c] = o;
  }
}

// K=64: row = 8 uint4; 8 subgroups of 8 lanes; 8 edges per load instr.
__global__ __launch_bounds__(256)
void k_agg64(const unsigned short* __restrict__ h, const int* __restrict__ row_off,
             const int* __restrict__ esrc, const float* __restrict__ deg_inv,
             unsigned short* __restrict__ agg, int N) {
  const int node = blockIdx.x * 4 + (threadIdx.x >> 6);
  if (node >= N) return;
  const int lane = threadIdx.x & 63;
  const int g = lane >> 3, c = lane & 7;
  const int s0 = row_off[node], s1 = row_off[node + 1];
  const uint4* hp = (const uint4*)h;
  float acc[8] = {0.f, 0.f, 0.f, 0.f, 0.f, 0.f, 0.f, 0.f};
  for (int i = s0; i < s1; i += 16) {
    int el = i + (lane & 15);
    if (el >= s1) el = s1 - 1;
    const int ev = esrc[el];
    uint4 v[2];
#pragma unroll
    for (int u = 0; u < 2; ++u) {
      if (i + u * 8 < s1) {
        const int e = __shfl(ev, u * 8 + g);
        v[u] = hp[(size_t)e * 8 + c];
      }
    }
#pragma unroll
    for (int u = 0; u < 2; ++u)
      if (i + u * 8 + g < s1) acc_u4(acc, v[u]);
  }
#pragma unroll
  for (int j = 0; j < 8; ++j) {
    acc[j] += __shfl_xor(acc[j], 8);
    acc[j] += __shfl_xor(acc[j], 16);
    acc[j] += __shfl_xor(acc[j], 32);
  }
  if (g == 0) {
    const float di = deg_inv[node];
    uint4 o;
    o.x = packbf(acc[0] * di, acc[1] * di);
    o.y = packbf(acc[2] * di, acc[3] * di);
    o.z = packbf(acc[4] * di, acc[5] * di);
    o.w = packbf(acc[6] * di, acc[7] * di);
    ((uint4*)agg)[(size_t)node * 8 + c] = o;
  }
}

// L1 fused post-transform aggregate: z = [Zl | Yr] (N x 128 bf16).
// out[n][0..63] = relu(deg_inv[n] * sum_e Zl[src(e)] + Yr[n] + bias).
__global__ __launch_bounds__(256)
void k_agg_post64(const unsigned short* __restrict__ z, const int* __restrict__ row_off,
                  const int* __restrict__ esrc, const float* __restrict__ deg_inv,
                  const float* __restrict__ bias, unsigned short* __restrict__ out, int N) {
  const int node = blockIdx.x * 4 + (threadIdx.x >> 6);
  if (node >= N) return;
  const int lane = threadIdx.x & 63;
  const int g = lane >> 3, c = lane & 7;
  const int s0 = row_off[node], s1 = row_off[node + 1];
  const uint4* zp = (const uint4*)z;   // row = 16 uint4; Zl = first 8
  float acc[8] = {0.f, 0.f, 0.f, 0.f, 0.f, 0.f, 0.f, 0.f};
  for (int i = s0; i < s1; i += 16) {
    int el = i + (lane & 15);
    if (el >= s1) el = s1 - 1;
    const int ev = esrc[el];
    uint4 v[2];
#pragma unroll
    for (int u = 0; u < 2; ++u) {
      if (i + u * 8 < s1) {
        const int e = __shfl(ev, u * 8 + g);
        v[u] = zp[(size_t)e * 16 + c];
      }
    }
#pragma unroll
    for (int u = 0; u < 2; ++u)
      if (i + u * 8 + g < s1) acc_u4(acc, v[u]);
  }
#pragma unroll
  for (int j = 0; j < 8; ++j) {
    acc[j] += __shfl_xor(acc[j], 8);
    acc[j] += __shfl_xor(acc[j], 16);
    acc[j] += __shfl_xor(acc[j], 32);
  }
  if (g == 0) {
    const float di = deg_inv[node];
    const uint4 yr = zp[(size_t)node * 16 + 8 + c];
    float y[8];
    y[0] = lo16(yr.x); y[1] = hi16(yr.x); y[2] = lo16(yr.y); y[3] = hi16(yr.y);
    y[4] = lo16(yr.z); y[5] = hi16(yr.z); y[6] = lo16(yr.w); y[7] = hi16(yr.w);
    float r[8];
#pragma unroll
    for (int j = 0; j < 8; ++j)
      r[j] = fmaxf(acc[j] * di + y[j] + bias[c * 8 + j], 0.f);
    uint4 o;
    o.x = packbf(r[0], r[1]);
    o.y = packbf(r[2], r[3]);
    o.z = packbf(r[4], r[5]);
    o.w = packbf(r[6], r[7]);
    ((uint4*)out)[(size_t)node * 8 + c] = o;
  }
}

// ---------------- fused SAGE GEMM ------------------------------------------
// FUSED=true : C = relu(A0@B0p^T + A1@B1p^T + bias)  (two phases)
// FUSED=false: C = A0@B0p^T                           (single phase, raw)
// Block: 128 rows x BN=WC*64 cols; 2 x WC waves; MFMA 32x32x16; BK=64.
// A staged in LDS (32KB double-buffer -> 5 blocks/CU); B read direct from
// global packed layout; per-tile B loads HOISTED before the MFMA loop.
// 1D grid, XCD-co-located decode: r8=bid&7, cb=(bid>>3)%NCB, rowp=((bid>>3)/NCB)*8+r8
template <int WC, int NCB, bool FUSED>
__global__ __launch_bounds__(WC * 128)
void k_sage_gemm(const unsigned short* __restrict__ A0, const unsigned short* __restrict__ B0,
                 const unsigned short* __restrict__ A1, const unsigned short* __restrict__ B1,
                 const float* __restrict__ bias, unsigned short* __restrict__ C,
                 int Nn, int K, int O) {
  constexpr int BN = WC * 64;
  constexpr int T = WC * 128;
  constexpr int ACH = 1024;            // A 16B-chunks per tile (128 rows x 8)
  constexpr int LPT = ACH / T;         // A chunks per thread per stage
  __shared__ char lds[2 * 16384];

  const int nrp = (Nn + 127) >> 7;
  const int bid = blockIdx.x;
  const int r8 = bid & 7;
  const int tb = bid >> 3;
  const int cb = tb % NCB;
  const int rowp = (tb / NCB) * 8 + r8;
  if (rowp >= nrp) return;

  const int tid = threadIdx.x;
  const int w = tid >> 6, lane = tid & 63;
  const int wr = w / WC, wc = w % WC;
  const int fr = lane & 31, fq = lane >> 5;
  const int row0 = rowp * 128 + wr * 64;
  const int colb = cb * BN;

  const int KT0 = K >> 6;        // 64-wide tiles per phase
  const int NT = FUSED ? 2 * KT0 : KT0;

  f32x16 acc[2][2];
#pragma unroll
  for (int m = 0; m < 2; ++m)
#pragma unroll
    for (int cn = 0; cn < 2; ++cn)
#pragma unroll
      for (int r = 0; r < 16; ++r) acc[m][cn][r] = 0.f;

  auto stage = [&](int buf, int t) {
    const unsigned short* Ab;
    int ktl;
    if (FUSED) {
      const int ph = (t >= KT0) ? 1 : 0;
      Ab = ph ? A1 : A0;
      ktl = t - ph * KT0;
    } else {
      Ab = A0; ktl = t;
    }
    char* lb = lds + buf * 16384;
#pragma unroll
    for (int i = 0; i < LPT; ++i) {
      const int ch = tid + i * T;
      const int ar = ch >> 3, s = ch & 7;           // LDS row, slot
      int g = rowp * 128 + ar;
      if (g >= Nn) g = Nn - 1;
      // inverse-swizzled global source; linear LDS dest
      gl_lds16(Ab + (size_t)g * K + ktl * 64 + ((s ^ (ar & 7)) << 3), lb + ch * 16);
    }
  };

  stage(0, 0);
#pragma unroll 1
  for (int t = 0; t < NT; ++t) {
    asm volatile("s_waitcnt vmcnt(0)" ::: "memory");
    __syncthreads();
    // B pointer for this tile (global, packed chunk-major)
    const unsigned short* Bp;
    int ktl;
    if (FUSED) {
      const int ph = (t >= KT0) ? 1 : 0;
      Bp = ph ? B1 : B0;
      ktl = t - ph * KT0;
    } else {
      Bp = B0; ktl = t;
    }
    const unsigned short* Bbase = Bp + (size_t)ktl * (O * 64) + (size_t)(colb + wc * 64) * 8;
    // HOIST: issue all 8 B loads for this tile up front (oldest in queue)
    bf16x8 bg[4][2];
#pragma unroll
    for (int k16i = 0; k16i < 4; ++k16i) {
      const int c = k16i * 2 + fq;                  // chunk 0..7
#pragma unroll
      for (int cn = 0; cn < 2; ++cn)
        bg[k16i][cn] = *(const bf16x8*)(Bbase + (size_t)c * (O * 8) + (cn * 32 + fr) * 8);
    }
    if (t + 1 < NT) stage((t + 1) & 1, t + 1);
    const char* lb = lds + (t & 1) * 16384;
#pragma unroll
    for (int k16i = 0; k16i < 4; ++k16i) {
      const int c = k16i * 2 + fq;                  // chunk 0..7
      bf16x8 af[2];
#pragma unroll
      for (int m = 0; m < 2; ++m) {
        const int rl = wr * 64 + m * 32 + fr;
        af[m] = *(const bf16x8*)(lb + rl * 128 + ((c ^ (rl & 7)) << 4));
      }
#pragma unroll
      for (int m = 0; m < 2; ++m)
#pragma unroll
        for (int cn = 0; cn < 2; ++cn)
          acc[m][cn] = __builtin_amdgcn_mfma_f32_32x32x16_bf16(af[m], bg[k16i][cn], acc[m][cn], 0, 0, 0);
    }
  }

  // epilogue. C/D map: col = lane&31, row = (reg&3) + 8*(reg>>2) + 4*(lane>>5).
#pragma unroll
  for (int cn = 0; cn < 2; ++cn) {
    const int col = colb + wc * 64 + cn * 32 + fr;
    float bb = 0.f;
    if (FUSED) bb = bias[col];
#pragma unroll
    for (int m = 0; m < 2; ++m) {
#pragma unroll
      for (int reg = 0; reg < 16; ++reg) {
        float v = acc[m][cn][reg];
        if (FUSED) v = fmaxf(v + bb, 0.f);
        const float nb = __shfl_xor(v, 1);
        const int row = row0 + m * 32 + (reg & 3) + 8 * (reg >> 2) + 4 * fq;
        if (!(lane & 1) && row < Nn) {
          *(unsigned int*)(C + (size_t)row * O + col) = packbf(v, nb);
        }
      }
    }
  }
}

// ---------------- head: logits(512->4) + softmax, 4 waves per block --------
// W4 (2048 f32 = 8KB) staged in LDS once per block.
__global__ __launch_bounds__(256)
void k_out_softmax(const unsigned short* __restrict__ h, const float* __restrict__ W4,
                   const float* __restrict__ b, float* __restrict__ out, int N) {
  __shared__ float w[2048];
  const int tid = threadIdx.x;
#pragma unroll
  for (int i = 0; i < 8; ++i) w[tid + i * 256] = W4[tid + i * 256];
  __syncthreads();
  const int n = blockIdx.x * 4 + (tid >> 6);
  if (n >= N) return;
  const int lane = tid & 63;
  const unsigned int* hp = (const unsigned int*)h + (size_t)n * 256;
  float a[4] = {0.f, 0.f, 0.f, 0.f};
#pragma unroll
  for (int it = 0; it < 4; ++it) {
    const unsigned int v = hp[it * 64 + lane];
    const float lo = lo16(v);
    const float hi = hi16(v);
    const int k = (it * 64 + lane) * 2;
#pragma unroll
    for (int c = 0; c < 4; ++c)
      a[c] += lo * w[c * 512 + k] + hi * w[c * 512 + k + 1];
  }
#pragma unroll
  for (int off = 32; off > 0; off >>= 1) {
#pragma unroll
    for (int c = 0; c < 4; ++c) a[c] += __shfl_down(a[c], off);
  }
  if (lane == 0) {
    const float l0 = a[0] + b[0], l1 = a[1] + b[1], l2 = a[2] + b[2], l3 = a[3] + b[3];
    const float m = fmaxf(fmaxf(l0, l1), fmaxf(l2, l3));
    const float e0 = expf(l0 - m), e1 = expf(l1 - m), e2 = expf(l2 - m), e3 = expf(l3 - m);
    const float inv = 1.0f / (e0 + e1 + e2 + e3);
    float4 r; r.x = e0 * inv; r.y = e1 * inv; r.z = e2 * inv; r.w = e3 * inv;
    *(float4*)(out + (size_t)n * 4) = r;
  }
}

// ---------------------------------------------------------------------------
extern "C" void kernel_launch(void* const* d_in, const int* in_sizes, int n_in,
                              void* d_out, int out_size, void* d_ws, size_t ws_size,
                              hipStream_t stream) {
  const float* x = (const float*)d_in[0];
  const float* Wl[5] = {(const float*)d_in[1], (const float*)d_in[4], (const float*)d_in[7],
                        (const float*)d_in[10], (const float*)d_in[13]};
  const float* bl[5] = {(const float*)d_in[2], (const float*)d_in[5], (const float*)d_in[8],
                        (const float*)d_in[11], (const float*)d_in[14]};
  const float* Wr[5] = {(const float*)d_in[3], (const float*)d_in[6], (const float*)d_in[9],
                        (const float*)d_in[12], (const float*)d_in[15]};
  const float* Wout = (const float*)d_in[16];
  const float* bout = (const float*)d_in[17];
  const int* eidx = (const int*)d_in[18];

  const int N = in_sizes[0] / 128;
  const int E = in_sizes[18] / 2;
  const int* srcI = eidx;
  const int* dstI = eidx + E;

  const int Kd[5] = {128, 128, 64, 128, 256};
  const int Od[5] = {128, 64, 128, 256, 512};

  // workspace carve-out (256B aligned)
  char* ws = (char*)d_ws;
  size_t p = 0;
  auto alloc = [&](size_t bytes) { size_t r = p; p += (bytes + 255) & ~(size_t)255; return r; };
  int*   deg     = (int*)(ws + alloc((size_t)N * 4));
  int*   row_off = (int*)(ws + alloc((size_t)(N + 1) * 4));
  int*   cursor  = (int*)(ws + alloc((size_t)N * 4));
  float* deg_inv = (float*)(ws + alloc((size_t)N * 4));
  int*   loc     = (int*)(ws + alloc((size_t)N * 4));
  int*   part    = (int*)(ws + alloc((size_t)1032 * 4));
  int*   esrc    = (int*)(ws + alloc((size_t)E * 4));
  unsigned short* xb = (unsigned short*)(ws + alloc((size_t)N * 128 * 2));
  unsigned short* wlb[5];
  unsigned short* wrb[5];
  for (int l = 0; l < 5; ++l) {
    wlb[l] = (unsigned short*)(ws + alloc((size_t)Od[l] * Kd[l] * 2));
    wrb[l] = (unsigned short*)(ws + alloc((size_t)Od[l] * Kd[l] * 2));
  }
  unsigned short* wcat1 = (unsigned short*)(ws + alloc((size_t)128 * 128 * 2));
  unsigned short* bufA = (unsigned short*)(ws + alloc((size_t)N * 512 * 2));
  unsigned short* bufB = (unsigned short*)(ws + alloc((size_t)N * 256 * 2));
  unsigned short* agg  = (unsigned short*)(ws + alloc((size_t)N * 256 * 2));
  (void)ws_size; (void)n_in; (void)out_size;

  // ---- conversions: x plain; weights packed chunk-major ----
  k_conv_x<<<128, 256, 0, stream>>>(x, xb, N * 128 / 4);
  PackJobs jobs;
  for (int l = 0; l < 5; ++l) {
    if (l == 1) {
      jobs.j[2] = {Wl[1], wcat1, 64, 128, 0, 128};   // Zl cols 0..63
      jobs.j[3] = {Wr[1], wcat1, 64, 128, 64, 128};  // Yr cols 64..127
    } else {
      jobs.j[2 * l]     = {Wl[l], wlb[l], Od[l], Kd[l], 0, Od[l]};
      jobs.j[2 * l + 1] = {Wr[l], wrb[l], Od[l], Kd[l], 0, Od[l]};
    }
  }
  k_pack_w<<<dim3(32, 10), 256, 0, stream>>>(jobs);

  // ---- CSR build (multi-block scan) ----
  hipMemsetAsync(deg, 0, (size_t)N * 4, stream);
  k_count_deg<<<idiv_up(E, 256), 256, 0, stream>>>(dstI, deg, E);
  const int nb = idiv_up(N, 1024);
  k_scan1<<<nb, 1024, 0, stream>>>(deg, loc, part, N);
  k_scan2<<<1, 1024, 0, stream>>>(part, nb);
  k_scan3<<<idiv_up(N + 1, 256), 256, 0, stream>>>(deg, loc, part, row_off, cursor, deg_inv, N, nb);
  k_fill_csr<<<idiv_up(E, 256), 256, 0, stream>>>(srcI, dstI, cursor, esrc, E);

  const int gx8 = 8 * ((idiv_up(N, 128) + 7) / 8);   // padded row-panel grid

  // ---- layer 0: K=128, O=128 ----
  k_agg128<<<idiv_up(N, 4), 256, 0, stream>>>(xb, row_off, esrc, deg_inv, agg, N);
  k_sage_gemm<2, 1, true><<<gx8, 256, 0, stream>>>(agg, wlb[0], xb, wrb[0], bl[0], bufA, N, 128, 128);

  // ---- layer 1 (linearity swap): Z|Yr = h1 @ [Wl;Wr]^T, then fused agg ----
  k_sage_gemm<2, 1, false><<<gx8, 256, 0, stream>>>(bufA, wcat1, bufA, wcat1, bl[1], agg, N, 128, 128);
  k_agg_post64<<<idiv_up(N, 4), 256, 0, stream>>>(agg, row_off, esrc, deg_inv, bl[1], bufB, N);

  // ---- layer 2: K=64, O=128 ----
  k_agg64<<<idiv_up(N, 4), 256, 0, stream>>>(bufB, row_off, esrc, deg_inv, agg, N);
  k_sage_gemm<2, 1, true><<<gx8, 256, 0, stream>>>(agg, wlb[2], bufB, wrb[2], bl[2], bufA, N, 64, 128);

  // ---- layer 3: K=128, O=256 (2 col-blocks, XCD-co-located) ----
  k_agg128<<<idiv_up(N, 4), 256, 0, stream>>>(bufA, row_off, esrc, deg_inv, agg, N);
  k_sage_gemm<2, 2, true><<<2 * gx8, 256, 0, stream>>>(agg, wlb[3], bufA, wrb[3], bl[3], bufB, N, 128, 256);

  // ---- layer 4: K=256, O=512 (4 col-blocks, XCD-co-located) ----
  k_agg256<<<idiv_up(N, 4), 256, 0, stream>>>(bufB, row_off, esrc, deg_inv, agg, N);
  k_sage_gemm<2, 4, true><<<4 * gx8, 256, 0, stream>>>(agg, wlb[4], bufB, wrb[4], bl[4], bufA, N, 256, 512);

  k_out_softmax<<<idiv_up(N, 4), 256, 0, stream>>>(bufA, Wout, bout, (float*)d_out, N);
}

// Round 14
// 393.757 us; speedup vs baseline: 1.4893x; 1.0224x over previous
//
#include <hip/hip_runtime.h>
#include <hip/hip_bf16.h>
#include <cstdint>
#include <cstddef>

// ---------------------------------------------------------------------------
// SAGE GNN forward, bf16 MFMA 32x32x16, LDS-staged GEMM, BK=64.
//  - GEMM: round-6 schedule + XCD-co-located col-blocks; B direct from global
//    (packed, L2-resident), per-tile B loads hoisted
//  - L1: linearity swap (raw GEMM then 64-wide fused aggregate)
//  - aggregates: uint4 lanes, 32-edge shfl-broadcast batches (deep MLP)
//  - CSR: x4-batched atomics in count/fill (independent chains per thread)
// ---------------------------------------------------------------------------

typedef short bf16x8 __attribute__((ext_vector_type(8)));   // 8 bf16 = 4 VGPRs
typedef float f32x16 __attribute__((ext_vector_type(16)));

static inline int idiv_up(int a, int b) { return (a + b - 1) / b; }

static __device__ __forceinline__ float bf2f(unsigned short u) {
  union { unsigned int i; float f; } v; v.i = ((unsigned int)u) << 16; return v.f;
}
static __device__ __forceinline__ unsigned short f2bf(float f) {
  union { float f; unsigned int i; } v; v.f = f;
  return (unsigned short)((v.i + 0x7FFFu + ((v.i >> 16) & 1u)) >> 16);  // RNE
}
static __device__ __forceinline__ float lo16(unsigned int u) { return bf2f((unsigned short)(u & 0xffffu)); }
static __device__ __forceinline__ float hi16(unsigned int u) { return bf2f((unsigned short)(u >> 16)); }
static __device__ __forceinline__ unsigned int packbf(float a, float b) {
  return (unsigned int)f2bf(a) | ((unsigned int)f2bf(b) << 16);
}

// async global->LDS, 16B per lane. LDS dest: wave-uniform base + lane*16.
static __device__ __forceinline__ void gl_lds16(const void* g, void* l) {
  typedef __attribute__((address_space(3))) unsigned int lds_u32;
  typedef __attribute__((address_space(1))) const unsigned int glb_u32;
  __builtin_amdgcn_global_load_lds((glb_u32*)(uintptr_t)g,
                                   (lds_u32*)(unsigned int)(uintptr_t)l, 16, 0, 0);
}

// ---------------- CSR build ----------------
// x4 edges per thread (strided): 4 independent atomics in flight per thread.
__global__ void k_count_deg(const int* __restrict__ dst, int* __restrict__ deg, int E) {
  const int T = gridDim.x * blockDim.x;
  const int e0 = blockIdx.x * blockDim.x + threadIdx.x;
#pragma unroll
  for (int j = 0; j < 4; ++j) {
    const int e = e0 + j * T;
    if (e < E) atomicAdd(deg + dst[e], 1);
  }
}

// pass 1: per-1024-block inclusive scan -> loc; block total -> part[bid]
__global__ __launch_bounds__(1024)
void k_scan1(const int* __restrict__ deg, int* __restrict__ loc, int* __restrict__ part, int n) {
  __shared__ int wsum[16];
  const int tid = threadIdx.x;
  const int lane = tid & 63, wid = tid >> 6;
  const int i = blockIdx.x * 1024 + tid;
  const int v = (i < n) ? deg[i] : 0;
  int incl = v;
#pragma unroll
  for (int off = 1; off < 64; off <<= 1) {
    int t = __shfl_up(incl, off);
    if (lane >= off) incl += t;
  }
  if (lane == 63) wsum[wid] = incl;
  __syncthreads();
  if (wid == 0) {
    int wv = (lane < 16) ? wsum[lane] : 0;
#pragma unroll
    for (int off = 1; off < 16; off <<= 1) {
      int t = __shfl_up(wv, off);
      if (lane >= off) wv += t;
    }
    if (lane < 16) wsum[lane] = wv;
  }
  __syncthreads();
  const int woff = (wid > 0) ? wsum[wid - 1] : 0;
  if (i < n) loc[i] = woff + incl;      // inclusive within block
  if (tid == 1023) part[blockIdx.x] = woff + incl;
}

// pass 2: single block scans nb (<=1024) partials -> exclusive; part[nb]=total
__global__ __launch_bounds__(1024)
void k_scan2(int* __restrict__ part, int nb) {
  __shared__ int wsum[16];
  const int tid = threadIdx.x;
  const int lane = tid & 63, wid = tid >> 6;
  const int v = (tid < nb) ? part[tid] : 0;
  int incl = v;
#pragma unroll
  for (int off = 1; off < 64; off <<= 1) {
    int t = __shfl_up(incl, off);
    if (lane >= off) incl += t;
  }
  if (lane == 63) wsum[wid] = incl;
  __syncthreads();
  if (wid == 0) {
    int wv = (lane < 16) ? wsum[lane] : 0;
#pragma unroll
    for (int off = 1; off < 16; off <<= 1) {
      int t = __shfl_up(wv, off);
      if (lane >= off) wv += t;
    }
    if (lane < 16) wsum[lane] = wv;
  }
  __syncthreads();
  const int woff = (wid > 0) ? wsum[wid - 1] : 0;
  if (tid < nb) part[tid] = woff + incl - v;  // exclusive
  if (tid == 0) part[nb] = wsum[15];          // total
}

// pass 3: apply offsets; emit row_off / cursor / deg_inv
__global__ __launch_bounds__(256)
void k_scan3(const int* __restrict__ deg, const int* __restrict__ loc, const int* __restrict__ part,
             int* __restrict__ row_off, int* __restrict__ cursor, float* __restrict__ deg_inv,
             int n, int nb) {
  const int i = blockIdx.x * blockDim.x + threadIdx.x;
  if (i < n) {
    const int v = deg[i];
    const int ro = part[i >> 10] + loc[i] - v;
    row_off[i] = ro;
    cursor[i] = ro;
    deg_inv[i] = 1.0f / (float)((v > 1) ? v : 1);
  }
  if (i == 0) row_off[n] = part[nb];
}

// x4 edges per thread: gather inputs, 4 independent atomic-returns, 4 stores.
__global__ void k_fill_csr(const int* __restrict__ src, const int* __restrict__ dst,
                           int* __restrict__ cursor, int* __restrict__ esrc, int E) {
  const int T = gridDim.x * blockDim.x;
  const int e0 = blockIdx.x * blockDim.x + threadIdx.x;
  int dv[4], sv[4], pv[4];
#pragma unroll
  for (int j = 0; j < 4; ++j) {
    const int e = e0 + j * T;
    if (e < E) { dv[j] = dst[e]; sv[j] = src[e]; }
  }
#pragma unroll
  for (int j = 0; j < 4; ++j) {
    const int e = e0 + j * T;
    if (e < E) pv[j] = atomicAdd(cursor + dv[j], 1);
  }
#pragma unroll
  for (int j = 0; j < 4; ++j) {
    const int e = e0 + j * T;
    if (e < E) esrc[pv[j]] = sv[j];
  }
}

// ---------------- x: f32 -> bf16 plain conversion --------------------------
__global__ __launch_bounds__(256)
void k_conv_x(const float* __restrict__ src, unsigned short* __restrict__ dst, int n4) {
  for (int i = blockIdx.x * blockDim.x + threadIdx.x; i < n4; i += gridDim.x * blockDim.x) {
    const float4 v = *((const float4*)src + i);
    uint2 o;
    o.x = packbf(v.x, v.y);
    o.y = packbf(v.z, v.w);
    *((uint2*)dst + i) = o;
  }
}

// ---------------- weights: f32 -> bf16 packed chunk-major ------------------
// dst idx (bf16 units) = kt64*(Opack*64) + chunk*(Opack*8) + (col+colOff)*8 + j
// holds src[col][kt64*64 + chunk*8 + j], chunk in 0..7.
struct PackJob { const float* src; unsigned short* dst; int O; int K; int colOff; int Opack; };
struct PackJobs { PackJob j[10]; };

__global__ __launch_bounds__(256)
void k_pack_w(PackJobs jobs) {
  const PackJob J = jobs.j[blockIdx.y];
  const int total = J.O * J.K / 2;  // u32 outputs, source-major
  for (int u = blockIdx.x * blockDim.x + threadIdx.x; u < total; u += gridDim.x * blockDim.x) {
    const int e = u * 2;
    const int col = e / J.K;
    const int k = e - col * J.K;
    const int kt = k >> 6, ch = (k >> 3) & 7, j = k & 7;
    const float f0 = J.src[(size_t)col * J.K + k];
    const float f1 = J.src[(size_t)col * J.K + k + 1];
    const int didx = kt * (J.Opack * 64) + ch * (J.Opack * 8) + (col + J.colOff) * 8 + j;
    ((unsigned int*)J.dst)[didx >> 1] = packbf(f0, f1);
  }
}

// ---------------- mean aggregation, bf16 in/out, f32 accum -----------------
static __device__ __forceinline__ void acc_u4(float* acc, const uint4& v) {
  acc[0] += lo16(v.x); acc[1] += hi16(v.x);
  acc[2] += lo16(v.y); acc[3] += hi16(v.y);
  acc[4] += lo16(v.z); acc[5] += hi16(v.z);
  acc[6] += lo16(v.w); acc[7] += hi16(v.w);
}

// K=128: row = 16 uint4; 4 subgroups of 16 lanes; 4 edges per load instr.
// 32-edge batches: up to 8 gathers in flight.
__global__ __launch_bounds__(256)
void k_agg128(const unsigned short* __restrict__ h, const int* __restrict__ row_off,
              const int* __restrict__ esrc, const float* __restrict__ deg_inv,
              unsigned short* __restrict__ agg, int N) {
  const int node = blockIdx.x * 4 + (threadIdx.x >> 6);
  if (node >= N) return;
  const int lane = threadIdx.x & 63;
  const int g = lane >> 4, c = lane & 15;
  const int s0 = row_off[node], s1 = row_off[node + 1];
  const uint4* hp = (const uint4*)h;
  float acc[8] = {0.f, 0.f, 0.f, 0.f, 0.f, 0.f, 0.f, 0.f};
  for (int i = s0; i < s1; i += 32) {
    int el = i + (lane & 31);
    if (el >= s1) el = s1 - 1;
    const int ev = esrc[el];
    uint4 v[8];
#pragma unroll
    for (int u = 0; u < 8; ++u) {
      if (i + u * 4 < s1) {                        // wave-uniform
        const int e = __shfl(ev, u * 4 + g);
        v[u] = hp[(size_t)e * 16 + c];
      }
    }
#pragma unroll
    for (int u = 0; u < 8; ++u)
      if (i + u * 4 + g < s1) acc_u4(acc, v[u]);
  }
#pragma unroll
  for (int j = 0; j < 8; ++j) {
    acc[j] += __shfl_xor(acc[j], 16);
    acc[j] += __shfl_xor(acc[j], 32);
  }
  if (g == 0) {
    const float di = deg_inv[node];
    uint4 o;
    o.x = packbf(acc[0] * di, acc[1] * di);
    o.y = packbf(acc[2] * di, acc[3] * di);
    o.z = packbf(acc[4] * di, acc[5] * di);
    o.w = packbf(acc[6] * di, acc[7] * di);
    ((uint4*)agg)[(size_t)node * 16 + c] = o;
  }
}

// K=256: row = 32 uint4; 2 subgroups of 32 lanes; 2 edges per load instr.
// 32-edge batches: up to 16 gathers in flight.
__global__ __launch_bounds__(256)
void k_agg256(const unsigned short* __restrict__ h, const int* __restrict__ row_off,
              const int* __restrict__ esrc, const float* __restrict__ deg_inv,
              unsigned short* __restrict__ agg, int N) {
  const int node = blockIdx.x * 4 + (threadIdx.x >> 6);
  if (node >= N) return;
  const int lane = threadIdx.x & 63;
  const int g = lane >> 5, c = lane & 31;
  const int s0 = row_off[node], s1 = row_off[node + 1];
  const uint4* hp = (const uint4*)h;
  float acc[8] = {0.f, 0.f, 0.f, 0.f, 0.f, 0.f, 0.f, 0.f};
  for (int i = s0; i < s1; i += 32) {
    int el = i + (lane & 31);
    if (el >= s1) el = s1 - 1;
    const int ev = esrc[el];
    uint4 v[16];
#pragma unroll
    for (int u = 0; u < 16; ++u) {
      if (i + u * 2 < s1) {                        // wave-uniform
        const int e = __shfl(ev, u * 2 + g);
        v[u] = hp[(size_t)e * 32 + c];
      }
    }
#pragma unroll
    for (int u = 0; u < 16; ++u)
      if (i + u * 2 + g < s1) acc_u4(acc, v[u]);
  }
#pragma unroll
  for (int j = 0; j < 8; ++j) acc[j] += __shfl_xor(acc[j], 32);
  if (g == 0) {
    const float di = deg_inv[node];
    uint4 o;
    o.x = packbf(acc[0] * di, acc[1] * di);
    o.y = packbf(acc[2] * di, acc[3] * di);
    o.z = packbf(acc[4] * di, acc[5] * di);
    o.w = packbf(acc[6] * di, acc[7] * di);
    ((uint4*)agg)[(size_t)node * 32 + c] = o;
  }
}

// K=64: row = 8 uint4; 8 subgroups of 8 lanes; 8 edges per load instr.
// 32-edge batches: up to 4 gathers in flight.
__global__ __launch_bounds__(256)
void k_agg64(const unsigned short* __restrict__ h, const int* __restrict__ row_off,
             const int* __restrict__ esrc, const float* __restrict__ deg_inv,
             unsigned short* __restrict__ agg, int N) {
  const int node = blockIdx.x * 4 + (threadIdx.x >> 6);
  if (node >= N) return;
  const int lane = threadIdx.x & 63;
  const int g = lane >> 3, c = lane & 7;
  const int s0 = row_off[node], s1 = row_off[node + 1];
  const uint4* hp = (const uint4*)h;
  float acc[8] = {0.f, 0.f, 0.f, 0.f, 0.f, 0.f, 0.f, 0.f};
  for (int i = s0; i < s1; i += 32) {
    int el = i + (lane & 31);
    if (el >= s1) el = s1 - 1;
    const int ev = esrc[el];
    uint4 v[4];
#pragma unroll
    for (int u = 0; u < 4; ++u) {
      if (i + u * 8 < s1) {                        // wave-uniform
        const int e = __shfl(ev, u * 8 + g);
        v[u] = hp[(size_t)e * 8 + c];
      }
    }
#pragma unroll
    for (int u = 0; u < 4; ++u)
      if (i + u * 8 + g < s1) acc_u4(acc, v[u]);
  }
#pragma unroll
  for (int j = 0; j < 8; ++j) {
    acc[j] += __shfl_xor(acc[j], 8);
    acc[j] += __shfl_xor(acc[j], 16);
    acc[j] += __shfl_xor(acc[j], 32);
  }
  if (g == 0) {
    const float di = deg_inv[node];
    uint4 o;
    o.x = packbf(acc[0] * di, acc[1] * di);
    o.y = packbf(acc[2] * di, acc[3] * di);
    o.z = packbf(acc[4] * di, acc[5] * di);
    o.w = packbf(acc[6] * di, acc[7] * di);
    ((uint4*)agg)[(size_t)node * 8 + c] = o;
  }
}

// L1 fused post-transform aggregate: z = [Zl | Yr] (N x 128 bf16).
// out[n][0..63] = relu(deg_inv[n] * sum_e Zl[src(e)] + Yr[n] + bias).
__global__ __launch_bounds__(256)
void k_agg_post64(const unsigned short* __restrict__ z, const int* __restrict__ row_off,
                  const int* __restrict__ esrc, const float* __restrict__ deg_inv,
                  const float* __restrict__ bias, unsigned short* __restrict__ out, int N) {
  const int node = blockIdx.x * 4 + (threadIdx.x >> 6);
  if (node >= N) return;
  const int lane = threadIdx.x & 63;
  const int g = lane >> 3, c = lane & 7;
  const int s0 = row_off[node], s1 = row_off[node + 1];
  const uint4* zp = (const uint4*)z;   // row = 16 uint4; Zl = first 8
  float acc[8] = {0.f, 0.f, 0.f, 0.f, 0.f, 0.f, 0.f, 0.f};
  for (int i = s0; i < s1; i += 32) {
    int el = i + (lane & 31);
    if (el >= s1) el = s1 - 1;
    const int ev = esrc[el];
    uint4 v[4];
#pragma unroll
    for (int u = 0; u < 4; ++u) {
      if (i + u * 8 < s1) {
        const int e = __shfl(ev, u * 8 + g);
        v[u] = zp[(size_t)e * 16 + c];
      }
    }
#pragma unroll
    for (int u = 0; u < 4; ++u)
      if (i + u * 8 + g < s1) acc_u4(acc, v[u]);
  }
#pragma unroll
  for (int j = 0; j < 8; ++j) {
    acc[j] += __shfl_xor(acc[j], 8);
    acc[j] += __shfl_xor(acc[j], 16);
    acc[j] += __shfl_xor(acc[j], 32);
  }
  if (g == 0) {
    const float di = deg_inv[node];
    const uint4 yr = zp[(size_t)node * 16 + 8 + c];
    float y[8];
    y[0] = lo16(yr.x); y[1] = hi16(yr.x); y[2] = lo16(yr.y); y[3] = hi16(yr.y);
    y[4] = lo16(yr.z); y[5] = hi16(yr.z); y[6] = lo16(yr.w); y[7] = hi16(yr.w);
    float r[8];
#pragma unroll
    for (int j = 0; j < 8; ++j)
      r[j] = fmaxf(acc[j] * di + y[j] + bias[c * 8 + j], 0.f);
    uint4 o;
    o.x = packbf(r[0], r[1]);
    o.y = packbf(r[2], r[3]);
    o.z = packbf(r[4], r[5]);
    o.w = packbf(r[6], r[7]);
    ((uint4*)out)[(size_t)node * 8 + c] = o;
  }
}

// ---------------- fused SAGE GEMM ------------------------------------------
// FUSED=true : C = relu(A0@B0p^T + A1@B1p^T + bias)  (two phases)
// FUSED=false: C = A0@B0p^T                           (single phase, raw)
// Block: 128 rows x BN=WC*64 cols; 2 x WC waves; MFMA 32x32x16; BK=64.
// A staged in LDS (32KB double-buffer -> 5 blocks/CU); B read direct from
// global packed layout; per-tile B loads HOISTED before the MFMA loop.
// 1D grid, XCD-co-located decode: r8=bid&7, cb=(bid>>3)%NCB, rowp=((bid>>3)/NCB)*8+r8
template <int WC, int NCB, bool FUSED>
__global__ __launch_bounds__(WC * 128)
void k_sage_gemm(const unsigned short* __restrict__ A0, const unsigned short* __restrict__ B0,
                 const unsigned short* __restrict__ A1, const unsigned short* __restrict__ B1,
                 const float* __restrict__ bias, unsigned short* __restrict__ C,
                 int Nn, int K, int O) {
  constexpr int BN = WC * 64;
  constexpr int T = WC * 128;
  constexpr int ACH = 1024;            // A 16B-chunks per tile (128 rows x 8)
  constexpr int LPT = ACH / T;         // A chunks per thread per stage
  __shared__ char lds[2 * 16384];

  const int nrp = (Nn + 127) >> 7;
  const int bid = blockIdx.x;
  const int r8 = bid & 7;
  const int tb = bid >> 3;
  const int cb = tb % NCB;
  const int rowp = (tb / NCB) * 8 + r8;
  if (rowp >= nrp) return;

  const int tid = threadIdx.x;
  const int w = tid >> 6, lane = tid & 63;
  const int wr = w / WC, wc = w % WC;
  const int fr = lane & 31, fq = lane >> 5;
  const int row0 = rowp * 128 + wr * 64;
  const int colb = cb * BN;

  const int KT0 = K >> 6;        // 64-wide tiles per phase
  const int NT = FUSED ? 2 * KT0 : KT0;

  f32x16 acc[2][2];
#pragma unroll
  for (int m = 0; m < 2; ++m)
#pragma unroll
    for (int cn = 0; cn < 2; ++cn)
#pragma unroll
      for (int r = 0; r < 16; ++r) acc[m][cn][r] = 0.f;

  auto stage = [&](int buf, int t) {
    const unsigned short* Ab;
    int ktl;
    if (FUSED) {
      const int ph = (t >= KT0) ? 1 : 0;
      Ab = ph ? A1 : A0;
      ktl = t - ph * KT0;
    } else {
      Ab = A0; ktl = t;
    }
    char* lb = lds + buf * 16384;
#pragma unroll
    for (int i = 0; i < LPT; ++i) {
      const int ch = tid + i * T;
      const int ar = ch >> 3, s = ch & 7;           // LDS row, slot
      int g = rowp * 128 + ar;
      if (g >= Nn) g = Nn - 1;
      // inverse-swizzled global source; linear LDS dest
      gl_lds16(Ab + (size_t)g * K + ktl * 64 + ((s ^ (ar & 7)) << 3), lb + ch * 16);
    }
  };

  stage(0, 0);
#pragma unroll 1
  for (int t = 0; t < NT; ++t) {
    asm volatile("s_waitcnt vmcnt(0)" ::: "memory");
    __syncthreads();
    // B pointer for this tile (global, packed chunk-major)
    const unsigned short* Bp;
    int ktl;
    if (FUSED) {
      const int ph = (t >= KT0) ? 1 : 0;
      Bp = ph ? B1 : B0;
      ktl = t - ph * KT0;
    } else {
      Bp = B0; ktl = t;
    }
    const unsigned short* Bbase = Bp + (size_t)ktl * (O * 64) + (size_t)(colb + wc * 64) * 8;
    // HOIST: issue all 8 B loads for this tile up front (oldest in queue)
    bf16x8 bg[4][2];
#pragma unroll
    for (int k16i = 0; k16i < 4; ++k16i) {
      const int c = k16i * 2 + fq;                  // chunk 0..7
#pragma unroll
      for (int cn = 0; cn < 2; ++cn)
        bg[k16i][cn] = *(const bf16x8*)(Bbase + (size_t)c * (O * 8) + (cn * 32 + fr) * 8);
    }
    if (t + 1 < NT) stage((t + 1) & 1, t + 1);
    const char* lb = lds + (t & 1) * 16384;
#pragma unroll
    for (int k16i = 0; k16i < 4; ++k16i) {
      const int c = k16i * 2 + fq;                  // chunk 0..7
      bf16x8 af[2];
#pragma unroll
      for (int m = 0; m < 2; ++m) {
        const int rl = wr * 64 + m * 32 + fr;
        af[m] = *(const bf16x8*)(lb + rl * 128 + ((c ^ (rl & 7)) << 4));
      }
#pragma unroll
      for (int m = 0; m < 2; ++m)
#pragma unroll
        for (int cn = 0; cn < 2; ++cn)
          acc[m][cn] = __builtin_amdgcn_mfma_f32_32x32x16_bf16(af[m], bg[k16i][cn], acc[m][cn], 0, 0, 0);
    }
  }

  // epilogue. C/D map: col = lane&31, row = (reg&3) + 8*(reg>>2) + 4*(lane>>5).
#pragma unroll
  for (int cn = 0; cn < 2; ++cn) {
    const int col = colb + wc * 64 + cn * 32 + fr;
    float bb = 0.f;
    if (FUSED) bb = bias[col];
#pragma unroll
    for (int m = 0; m < 2; ++m) {
#pragma unroll
      for (int reg = 0; reg < 16; ++reg) {
        float v = acc[m][cn][reg];
        if (FUSED) v = fmaxf(v + bb, 0.f);
        const float nb = __shfl_xor(v, 1);
        const int row = row0 + m * 32 + (reg & 3) + 8 * (reg >> 2) + 4 * fq;
        if (!(lane & 1) && row < Nn) {
          *(unsigned int*)(C + (size_t)row * O + col) = packbf(v, nb);
        }
      }
    }
  }
}

// ---------------- head: logits(512->4) + softmax, 4 waves per block --------
// W4 (2048 f32 = 8KB) staged in LDS once per block.
__global__ __launch_bounds__(256)
void k_out_softmax(const unsigned short* __restrict__ h, const float* __restrict__ W4,
                   const float* __restrict__ b, float* __restrict__ out, int N) {
  __shared__ float w[2048];
  const int tid = threadIdx.x;
#pragma unroll
  for (int i = 0; i < 8; ++i) w[tid + i * 256] = W4[tid + i * 256];
  __syncthreads();
  const int n = blockIdx.x * 4 + (tid >> 6);
  if (n >= N) return;
  const int lane = tid & 63;
  const unsigned int* hp = (const unsigned int*)h + (size_t)n * 256;
  float a[4] = {0.f, 0.f, 0.f, 0.f};
#pragma unroll
  for (int it = 0; it < 4; ++it) {
    const unsigned int v = hp[it * 64 + lane];
    const float lo = lo16(v);
    const float hi = hi16(v);
    const int k = (it * 64 + lane) * 2;
#pragma unroll
    for (int c = 0; c < 4; ++c)
      a[c] += lo * w[c * 512 + k] + hi * w[c * 512 + k + 1];
  }
#pragma unroll
  for (int off = 32; off > 0; off >>= 1) {
#pragma unroll
    for (int c = 0; c < 4; ++c) a[c] += __shfl_down(a[c], off);
  }
  if (lane == 0) {
    const float l0 = a[0] + b[0], l1 = a[1] + b[1], l2 = a[2] + b[2], l3 = a[3] + b[3];
    const float m = fmaxf(fmaxf(l0, l1), fmaxf(l2, l3));
    const float e0 = expf(l0 - m), e1 = expf(l1 - m), e2 = expf(l2 - m), e3 = expf(l3 - m);
    const float inv = 1.0f / (e0 + e1 + e2 + e3);
    float4 r; r.x = e0 * inv; r.y = e1 * inv; r.z = e2 * inv; r.w = e3 * inv;
    *(float4*)(out + (size_t)n * 4) = r;
  }
}

// ---------------------------------------------------------------------------
extern "C" void kernel_launch(void* const* d_in, const int* in_sizes, int n_in,
                              void* d_out, int out_size, void* d_ws, size_t ws_size,
                              hipStream_t stream) {
  const float* x = (const float*)d_in[0];
  const float* Wl[5] = {(const float*)d_in[1], (const float*)d_in[4], (const float*)d_in[7],
                        (const float*)d_in[10], (const float*)d_in[13]};
  const float* bl[5] = {(const float*)d_in[2], (const float*)d_in[5], (const float*)d_in[8],
                        (const float*)d_in[11], (const float*)d_in[14]};
  const float* Wr[5] = {(const float*)d_in[3], (const float*)d_in[6], (const float*)d_in[9],
                        (const float*)d_in[12], (const float*)d_in[15]};
  const float* Wout = (const float*)d_in[16];
  const float* bout = (const float*)d_in[17];
  const int* eidx = (const int*)d_in[18];

  const int N = in_sizes[0] / 128;
  const int E = in_sizes[18] / 2;
  const int* srcI = eidx;
  const int* dstI = eidx + E;

  const int Kd[5] = {128, 128, 64, 128, 256};
  const int Od[5] = {128, 64, 128, 256, 512};

  // workspace carve-out (256B aligned)
  char* ws = (char*)d_ws;
  size_t p = 0;
  auto alloc = [&](size_t bytes) { size_t r = p; p += (bytes + 255) & ~(size_t)255; return r; };
  int*   deg     = (int*)(ws + alloc((size_t)N * 4));
  int*   row_off = (int*)(ws + alloc((size_t)(N + 1) * 4));
  int*   cursor  = (int*)(ws + alloc((size_t)N * 4));
  float* deg_inv = (float*)(ws + alloc((size_t)N * 4));
  int*   loc     = (int*)(ws + alloc((size_t)N * 4));
  int*   part    = (int*)(ws + alloc((size_t)1032 * 4));
  int*   esrc    = (int*)(ws + alloc((size_t)E * 4));
  unsigned short* xb = (unsigned short*)(ws + alloc((size_t)N * 128 * 2));
  unsigned short* wlb[5];
  unsigned short* wrb[5];
  for (int l = 0; l < 5; ++l) {
    wlb[l] = (unsigned short*)(ws + alloc((size_t)Od[l] * Kd[l] * 2));
    wrb[l] = (unsigned short*)(ws + alloc((size_t)Od[l] * Kd[l] * 2));
  }
  unsigned short* wcat1 = (unsigned short*)(ws + alloc((size_t)128 * 128 * 2));
  unsigned short* bufA = (unsigned short*)(ws + alloc((size_t)N * 512 * 2));
  unsigned short* bufB = (unsigned short*)(ws + alloc((size_t)N * 256 * 2));
  unsigned short* agg  = (unsigned short*)(ws + alloc((size_t)N * 256 * 2));
  (void)ws_size; (void)n_in; (void)out_size;

  // ---- conversions: x plain; weights packed chunk-major ----
  k_conv_x<<<128, 256, 0, stream>>>(x, xb, N * 128 / 4);
  PackJobs jobs;
  for (int l = 0; l < 5; ++l) {
    if (l == 1) {
      jobs.j[2] = {Wl[1], wcat1, 64, 128, 0, 128};   // Zl cols 0..63
      jobs.j[3] = {Wr[1], wcat1, 64, 128, 64, 128};  // Yr cols 64..127
    } else {
      jobs.j[2 * l]     = {Wl[l], wlb[l], Od[l], Kd[l], 0, Od[l]};
      jobs.j[2 * l + 1] = {Wr[l], wrb[l], Od[l], Kd[l], 0, Od[l]};
    }
  }
  k_pack_w<<<dim3(32, 10), 256, 0, stream>>>(jobs);

  // ---- CSR build (multi-block scan; x4-batched atomics) ----
  hipMemsetAsync(deg, 0, (size_t)N * 4, stream);
  k_count_deg<<<idiv_up(E, 1024), 256, 0, stream>>>(dstI, deg, E);
  const int nb = idiv_up(N, 1024);
  k_scan1<<<nb, 1024, 0, stream>>>(deg, loc, part, N);
  k_scan2<<<1, 1024, 0, stream>>>(part, nb);
  k_scan3<<<idiv_up(N + 1, 256), 256, 0, stream>>>(deg, loc, part, row_off, cursor, deg_inv, N, nb);
  k_fill_csr<<<idiv_up(E, 1024), 256, 0, stream>>>(srcI, dstI, cursor, esrc, E);

  const int gx8 = 8 * ((idiv_up(N, 128) + 7) / 8);   // padded row-panel grid

  // ---- layer 0: K=128, O=128 ----
  k_agg128<<<idiv_up(N, 4), 256, 0, stream>>>(xb, row_off, esrc, deg_inv, agg, N);
  k_sage_gemm<2, 1, true><<<gx8, 256, 0, stream>>>(agg, wlb[0], xb, wrb[0], bl[0], bufA, N, 128, 128);

  // ---- layer 1 (linearity swap): Z|Yr = h1 @ [Wl;Wr]^T, then fused agg ----
  k_sage_gemm<2, 1, false><<<gx8, 256, 0, stream>>>(bufA, wcat1, bufA, wcat1, bl[1], agg, N, 128, 128);
  k_agg_post64<<<idiv_up(N, 4), 256, 0, stream>>>(agg, row_off, esrc, deg_inv, bl[1], bufB, N);

  // ---- layer 2: K=64, O=128 ----
  k_agg64<<<idiv_up(N, 4), 256, 0, stream>>>(bufB, row_off, esrc, deg_inv, agg, N);
  k_sage_gemm<2, 1, true><<<gx8, 256, 0, stream>>>(agg, wlb[2], bufB, wrb[2], bl[2], bufA, N, 64, 128);

  // ---- layer 3: K=128, O=256 (2 col-blocks, XCD-co-located) ----
  k_agg128<<<idiv_up(N, 4), 256, 0, stream>>>(bufA, row_off, esrc, deg_inv, agg, N);
  k_sage_gemm<2, 2, true><<<2 * gx8, 256, 0, stream>>>(agg, wlb[3], bufA, wrb[3], bl[3], bufB, N, 128, 256);

  // ---- layer 4: K=256, O=512 (4 col-blocks, XCD-co-located) ----
  k_agg256<<<idiv_up(N, 4), 256, 0, stream>>>(bufB, row_off, esrc, deg_inv, agg, N);
  k_sage_gemm<2, 4, true><<<4 * gx8, 256, 0, stream>>>(agg, wlb[4], bufB, wrb[4], bl[4], bufA, N, 256, 512);

  k_out_softmax<<<idiv_up(N, 4), 256, 0, stream>>>(bufA, Wout, bout, (float*)d_out, N);
}